// Round 1
// baseline (8471.141 us; speedup 1.0000x reference)
//
#include <hip/hip_runtime.h>

#define NN   50000
#define NE   800000
#define HID  128
#define NG   2500
#define DIN  261   // 2*HID + 1 + 4
#define TE   16
#define TN   16
#define TP   20    // padded tile stride (floats): 80B rows -> 16B aligned, banks spread

__device__ __forceinline__ float sigf(float x){ return 1.0f/(1.0f+__expf(-x)); }
__device__ __forceinline__ float siluf(float x){ return x/(1.0f+__expf(-x)); }

// mask[e] = 1 if sigmoid(p[inv[e]]) >= 0.5  (== p >= 0)
__global__ void mask_kernel(const float* __restrict__ p, const int* __restrict__ inv,
                            float* __restrict__ mask){
  int e = blockIdx.x*256 + threadIdx.x;
  if (e < NE) mask[e] = (p[inv[e]] >= 0.0f) ? 1.0f : 0.0f;
}

// h = x_feat @ emb_W + emb_b
__global__ void embed_kernel(const float* __restrict__ xf, const float* __restrict__ W,
                             const float* __restrict__ b, float* __restrict__ h){
  int n = blockIdx.x; int o = threadIdx.x;
  float s = b[o];
  #pragma unroll
  for (int i=0;i<11;++i) s = fmaf(xf[n*11+i], W[i*HID+o], s);
  h[(size_t)n*HID+o] = s;
}

__global__ __launch_bounds__(256) void edge_kernel(
    const float* __restrict__ h, const float* __restrict__ x,
    const float* __restrict__ ea, const float* __restrict__ mask,
    const int* __restrict__ eidx,              // [2][NE]: rows then cols
    const float* __restrict__ W1, const float* __restrict__ b1,
    const float* __restrict__ W2, const float* __restrict__ b2,
    const float* __restrict__ Wg, const float* __restrict__ bg,
    const float* __restrict__ Wc1, const float* __restrict__ bc1,
    const float* __restrict__ Wc2, const float* __restrict__ cb2,
    float* __restrict__ m_aggr, float* __restrict__ x_out)
{
  __shared__ float msgT[DIN][TP];   // msg_in transposed; rows 0..127 reused as m^T later
  __shared__ float hidT[HID][TP];   // hidden1, later hidden2
  __shared__ float red[16][TE];
  __shared__ float cdS[TE][3];
  __shared__ int   colS[TE];
  __shared__ float maskS[TE];
  __shared__ float scaleS[TE];

  const int t  = threadIdx.x;
  const int e0 = blockIdx.x * TE;

  // ---------- load: msg_in = [h[col], h[row], dist, edge_attr], transposed ----------
  {
    int el = t >> 4, sub = t & 15;
    int e = e0 + el;
    int r = eidx[e], c = eidx[NE + e];
    if (sub == 0){ colS[el] = c; maskS[el] = mask[e]; }
    if (sub == 1){
      float dx = x[c*3+0]-x[r*3+0];
      float dy = x[c*3+1]-x[r*3+1];
      float dz = x[c*3+2]-x[r*3+2];
      cdS[el][0]=dx; cdS[el][1]=dy; cdS[el][2]=dz;
      msgT[256][el] = sqrtf(dx*dx+dy*dy+dz*dz);
    }
    const float* hc = h + (size_t)c*HID;
    const float* hr = h + (size_t)r*HID;
    for (int i=sub;i<HID;i+=16){
      msgT[i][el]     = hc[i];
      msgT[128+i][el] = hr[i];
    }
    if (sub < 4) msgT[257+sub][el] = ea[(size_t)e*4 + sub];
  }
  __syncthreads();

  const int o  = t & 127;
  const int eb = (t >> 7) * 8;   // this thread's 8 edges

  // ---------- P1: hidden = silu(msg_in @ W1 + b1) ----------
  float acc[8];
  #pragma unroll
  for (int j=0;j<8;++j) acc[j] = b1[o];
  #pragma unroll 4
  for (int i=0;i<DIN;++i){
    float w = W1[i*HID+o];
    float4 a0 = *reinterpret_cast<const float4*>(&msgT[i][eb]);
    float4 a1 = *reinterpret_cast<const float4*>(&msgT[i][eb+4]);
    acc[0]=fmaf(a0.x,w,acc[0]); acc[1]=fmaf(a0.y,w,acc[1]);
    acc[2]=fmaf(a0.z,w,acc[2]); acc[3]=fmaf(a0.w,w,acc[3]);
    acc[4]=fmaf(a1.x,w,acc[4]); acc[5]=fmaf(a1.y,w,acc[5]);
    acc[6]=fmaf(a1.z,w,acc[6]); acc[7]=fmaf(a1.w,w,acc[7]);
  }
  #pragma unroll
  for (int j=0;j<8;++j) hidT[o][eb+j] = siluf(acc[j]);
  __syncthreads();

  // ---------- P2: m = silu(hidden @ W2 + b2) ----------
  float mreg[8];
  #pragma unroll
  for (int j=0;j<8;++j) mreg[j] = b2[o];
  #pragma unroll 4
  for (int k=0;k<HID;++k){
    float w = W2[k*HID+o];
    float4 a0 = *reinterpret_cast<const float4*>(&hidT[k][eb]);
    float4 a1 = *reinterpret_cast<const float4*>(&hidT[k][eb+4]);
    mreg[0]=fmaf(a0.x,w,mreg[0]); mreg[1]=fmaf(a0.y,w,mreg[1]);
    mreg[2]=fmaf(a0.z,w,mreg[2]); mreg[3]=fmaf(a0.w,w,mreg[3]);
    mreg[4]=fmaf(a1.x,w,mreg[4]); mreg[5]=fmaf(a1.y,w,mreg[5]);
    mreg[6]=fmaf(a1.z,w,mreg[6]); mreg[7]=fmaf(a1.w,w,mreg[7]);
  }
  #pragma unroll
  for (int j=0;j<8;++j){ mreg[j] = siluf(mreg[j]); msgT[o][eb+j] = mreg[j]; }
  __syncthreads();

  // ---------- gate = sigmoid(m @ Wg + bg)  (pre-mask m) ----------
  {
    int e = t & 15, oi = t >> 4;
    float partial = 0.f;
    #pragma unroll
    for (int j=0;j<8;++j){ int oo = oi + 16*j; partial = fmaf(msgT[oo][e], Wg[oo], partial); }
    red[oi][e] = partial;
  }
  __syncthreads();
  if (t < TE){
    float g = bg[0];
    #pragma unroll
    for (int oi=0;oi<16;++oi) g += red[oi][t];
    scaleS[t] = sigf(g) * maskS[t];
  }
  __syncthreads();

  // ---------- m *= gate*mask; scatter-add into m_aggr[col] ----------
  #pragma unroll
  for (int j=0;j<8;++j){
    int e = eb + j;
    float v = mreg[j]*scaleS[e];
    msgT[o][e] = v;                                  // post-mask m^T for cw path
    atomicAdd(&m_aggr[(size_t)colS[e]*HID + o], v);
  }
  __syncthreads();

  // ---------- hidden2 = silu(m @ Wc1 + bc1) ----------
  float acc3[8];
  #pragma unroll
  for (int j=0;j<8;++j) acc3[j] = bc1[o];
  #pragma unroll 4
  for (int k=0;k<HID;++k){
    float w = Wc1[k*HID+o];
    float4 a0 = *reinterpret_cast<const float4*>(&msgT[k][eb]);
    float4 a1 = *reinterpret_cast<const float4*>(&msgT[k][eb+4]);
    acc3[0]=fmaf(a0.x,w,acc3[0]); acc3[1]=fmaf(a0.y,w,acc3[1]);
    acc3[2]=fmaf(a0.z,w,acc3[2]); acc3[3]=fmaf(a0.w,w,acc3[3]);
    acc3[4]=fmaf(a1.x,w,acc3[4]); acc3[5]=fmaf(a1.y,w,acc3[5]);
    acc3[6]=fmaf(a1.z,w,acc3[6]); acc3[7]=fmaf(a1.w,w,acc3[7]);
  }
  #pragma unroll
  for (int j=0;j<8;++j) hidT[o][eb+j] = siluf(acc3[j]);
  __syncthreads();

  // ---------- cw = hidden2 @ Wc2 + cb2; x_out[col] += coord_diff * cw ----------
  {
    int e = t & 15, oi = t >> 4;
    float partial = 0.f;
    #pragma unroll
    for (int j=0;j<8;++j){ int oo = oi + 16*j; partial = fmaf(hidT[oo][e], Wc2[oo], partial); }
    red[oi][e] = partial;
  }
  __syncthreads();
  if (t < TE){
    float cw = cb2[0];
    #pragma unroll
    for (int oi=0;oi<16;++oi) cw += red[oi][t];
    int c = colS[t];
    atomicAdd(&x_out[c*3+0], cdS[t][0]*cw);
    atomicAdd(&x_out[c*3+1], cdS[t][1]*cw);
    atomicAdd(&x_out[c*3+2], cdS[t][2]*cw);
  }
}

// h += silu([h, m_aggr] @ Wn1 + bn1) @ Wn2 + bn2
__global__ __launch_bounds__(256) void node_kernel(
    float* __restrict__ h, const float* __restrict__ magg,
    const float* __restrict__ Wn1, const float* __restrict__ bn1,
    const float* __restrict__ Wn2, const float* __restrict__ bn2)
{
  __shared__ float inT[2*HID][TP];
  __shared__ float hidT[HID][TP];
  const int t  = threadIdx.x;
  const int n0 = blockIdx.x * TN;
  {
    int nl = t >> 4, sub = t & 15;
    int n = n0 + nl;
    const float* hp = h + (size_t)n*HID;
    const float* mp = magg + (size_t)n*HID;
    for (int i=sub;i<HID;i+=16){
      inT[i][nl]     = hp[i];
      inT[128+i][nl] = mp[i];
    }
  }
  __syncthreads();
  const int o  = t & 127;
  const int nb = (t >> 7) * 8;

  float acc[8];
  #pragma unroll
  for (int j=0;j<8;++j) acc[j] = bn1[o];
  #pragma unroll 4
  for (int i=0;i<2*HID;++i){
    float w = Wn1[i*HID+o];
    float4 a0 = *reinterpret_cast<const float4*>(&inT[i][nb]);
    float4 a1 = *reinterpret_cast<const float4*>(&inT[i][nb+4]);
    acc[0]=fmaf(a0.x,w,acc[0]); acc[1]=fmaf(a0.y,w,acc[1]);
    acc[2]=fmaf(a0.z,w,acc[2]); acc[3]=fmaf(a0.w,w,acc[3]);
    acc[4]=fmaf(a1.x,w,acc[4]); acc[5]=fmaf(a1.y,w,acc[5]);
    acc[6]=fmaf(a1.z,w,acc[6]); acc[7]=fmaf(a1.w,w,acc[7]);
  }
  #pragma unroll
  for (int j=0;j<8;++j) hidT[o][nb+j] = siluf(acc[j]);
  __syncthreads();

  float dh[8];
  #pragma unroll
  for (int j=0;j<8;++j) dh[j] = bn2[o];
  #pragma unroll 4
  for (int k=0;k<HID;++k){
    float w = Wn2[k*HID+o];
    float4 a0 = *reinterpret_cast<const float4*>(&hidT[k][nb]);
    float4 a1 = *reinterpret_cast<const float4*>(&hidT[k][nb+4]);
    dh[0]=fmaf(a0.x,w,dh[0]); dh[1]=fmaf(a0.y,w,dh[1]);
    dh[2]=fmaf(a0.z,w,dh[2]); dh[3]=fmaf(a0.w,w,dh[3]);
    dh[4]=fmaf(a1.x,w,dh[4]); dh[5]=fmaf(a1.y,w,dh[5]);
    dh[6]=fmaf(a1.z,w,dh[6]); dh[7]=fmaf(a1.w,w,dh[7]);
  }
  #pragma unroll
  for (int j=0;j<8;++j){
    int n = n0 + nb + j;
    h[(size_t)n*HID + o] = inT[o][nb+j] + dh[j];   // residual (inT rows 0..127 = old h)
  }
}

// segmented (batch is sorted) partial-reduce then atomics
__global__ void pool_kernel(const float* __restrict__ h, const int* __restrict__ batch,
                            float* __restrict__ sums, float* __restrict__ counts){
  int o  = threadIdx.x;
  int n0 = blockIdx.x * 16;
  int curg = batch[n0];
  float accv = 0.f, cnt = 0.f;
  for (int j=0;j<16;++j){
    int n = n0 + j;
    int g = batch[n];
    if (g != curg){
      atomicAdd(&sums[(size_t)curg*HID+o], accv);
      if (o==0) atomicAdd(&counts[curg], cnt);
      accv = 0.f; cnt = 0.f; curg = g;
    }
    accv += h[(size_t)n*HID+o];
    cnt  += 1.f;
  }
  atomicAdd(&sums[(size_t)curg*HID+o], accv);
  if (o==0) atomicAdd(&counts[curg], cnt);
}

__global__ void out_kernel(const float* __restrict__ sums, const float* __restrict__ counts,
                           const float* __restrict__ rW, const float* __restrict__ rb,
                           float* __restrict__ out){
  int g = blockIdx.x; int t = threadIdx.x;  // 64 threads
  float v = sums[(size_t)g*HID + t]*rW[t] + sums[(size_t)g*HID + 64 + t]*rW[64+t];
  #pragma unroll
  for (int off=32; off>0; off>>=1) v += __shfl_down(v, off);
  if (t==0) out[g] = v / fmaxf(counts[g], 1.0f) + rb[0];
}

extern "C" void kernel_launch(void* const* d_in, const int* in_sizes, int n_in,
                              void* d_out, int out_size, void* d_ws, size_t ws_size,
                              hipStream_t stream)
{
  const float* x_feat = (const float*)d_in[0];
  const float* pos    = (const float*)d_in[1];
  const float* eattr  = (const float*)d_in[2];
  const float* p      = (const float*)d_in[3];
  const float* embW   = (const float*)d_in[4];
  const float* embB   = (const float*)d_in[5];
  const float* eW1    = (const float*)d_in[6];
  const float* eb1    = (const float*)d_in[7];
  const float* eW2    = (const float*)d_in[8];
  const float* eb2    = (const float*)d_in[9];
  const float* gW     = (const float*)d_in[10];
  const float* gb     = (const float*)d_in[11];
  const float* nW1    = (const float*)d_in[12];
  const float* nb1    = (const float*)d_in[13];
  const float* nW2    = (const float*)d_in[14];
  const float* nb2    = (const float*)d_in[15];
  const float* cW1    = (const float*)d_in[16];
  const float* cb1    = (const float*)d_in[17];
  const float* cW2    = (const float*)d_in[18];
  const float* cb2    = (const float*)d_in[19];
  const float* rW     = (const float*)d_in[20];
  const float* rb     = (const float*)d_in[21];
  const int* eidx     = (const int*)d_in[22];
  const int* einv     = (const int*)d_in[23];
  const int* batch    = (const int*)d_in[24];

  float* ws = (float*)d_ws;
  float* h      = ws;  ws += (size_t)NN*HID;
  float* magg   = ws;  ws += (size_t)NN*HID;
  float* xA     = ws;  ws += NN*3;
  float* xB     = ws;  ws += NN*3;
  float* mask   = ws;  ws += NE;
  float* sums   = ws;  ws += (size_t)NG*HID;
  float* counts = ws;  ws += NG;

  hipMemcpyAsync(xA, pos, sizeof(float)*NN*3, hipMemcpyDeviceToDevice, stream);
  mask_kernel<<<(NE+255)/256, 256, 0, stream>>>(p, einv, mask);
  embed_kernel<<<NN, HID, 0, stream>>>(x_feat, embW, embB, h);

  float* xc = xA; float* xn = xB;
  for (int l=0;l<4;++l){
    hipMemsetAsync(magg, 0, sizeof(float)*(size_t)NN*HID, stream);
    hipMemcpyAsync(xn, xc, sizeof(float)*NN*3, hipMemcpyDeviceToDevice, stream);
    edge_kernel<<<NE/TE, 256, 0, stream>>>(h, xc, eattr, mask, eidx,
        eW1 + (size_t)l*DIN*HID, eb1 + l*HID,
        eW2 + (size_t)l*HID*HID, eb2 + l*HID,
        gW  + l*HID,             gb  + l,
        cW1 + (size_t)l*HID*HID, cb1 + l*HID,
        cW2 + l*HID,             cb2 + l,
        magg, xn);
    node_kernel<<<NN/TN, 256, 0, stream>>>(h, magg,
        nW1 + (size_t)l*2*HID*HID, nb1 + l*HID,
        nW2 + (size_t)l*HID*HID,   nb2 + l*HID);
    float* tmp = xc; xc = xn; xn = tmp;
  }
  hipMemsetAsync(sums, 0, sizeof(float)*((size_t)NG*HID + NG), stream);
  pool_kernel<<<NN/16, HID, 0, stream>>>(h, batch, sums, counts);
  out_kernel<<<NG, 64, 0, stream>>>(sums, counts, rW, rb, (float*)d_out);
}

// Round 2
// 3180.463 us; speedup vs baseline: 2.6635x; 2.6635x over previous
//
#include <hip/hip_runtime.h>

#define NN 50000
#define NE 800000
#define HID 128
#define NG 2500
#define NL 4
#define DIN 261
#define NKS1 9      // ceil(261/32) k-steps for GEMM1
#define NKS2 4      // 128/32
#define ME 64       // edges per block
#define MST 296     // msg row stride (shorts): 288 padded-K + 8 (odd quad count)
#define HST 136     // hid/m row stride (shorts): 128 + 8
#define TN 16
#define TP 20

typedef __attribute__((ext_vector_type(8))) short short8v;
typedef __attribute__((ext_vector_type(4))) float f32x4;

__device__ __forceinline__ float sigf(float x){ return 1.0f/(1.0f+__expf(-x)); }
__device__ __forceinline__ float siluf(float x){ return x/(1.0f+__expf(-x)); }
__device__ __forceinline__ short bfr(float x){           // f32 -> bf16 bits, RNE
  unsigned u = __float_as_uint(x);
  u += 0x7fffu + ((u>>16)&1u);
  return (short)(u>>16);
}
__device__ __forceinline__ float bf2f(short s){
  return __uint_as_float(((unsigned)(unsigned short)s)<<16);
}

// ---------------- weight prepack: [L][K][128] f32 -> [L][ks][o=128][kk=32] bf16 ----
__global__ void prepack_kernel(const float* __restrict__ W, short* __restrict__ out,
                               int K, int nks){
  int idx = blockIdx.x*256 + threadIdx.x;
  int total = NL*nks*HID*32;
  if (idx >= total) return;
  int kk = idx & 31;
  int o  = (idx>>5) & 127;
  int lks = idx >> 12;          // l*nks + ks
  int ks = lks % nks;
  int l  = lks / nks;
  int k = ks*32 + kk;
  float v = (k < K) ? W[((size_t)l*K + k)*HID + o] : 0.0f;
  out[idx] = bfr(v);
}

__global__ void mask_kernel(const float* __restrict__ p, const int* __restrict__ inv,
                            float* __restrict__ mask){
  int e = blockIdx.x*256 + threadIdx.x;
  if (e < NE) mask[e] = (p[inv[e]] >= 0.0f) ? 1.0f : 0.0f;
}

__global__ void embed_kernel(const float* __restrict__ xf, const float* __restrict__ W,
                             const float* __restrict__ b, float* __restrict__ h){
  int n = blockIdx.x; int o = threadIdx.x;
  float s = b[o];
  #pragma unroll
  for (int i=0;i<11;++i) s = fmaf(xf[n*11+i], W[i*HID+o], s);
  h[(size_t)n*HID+o] = s;
}

// ---------------- MFMA tile-GEMM: [64 x K] (LDS bf16) @ [K x 128] (prepacked) ------
// 4 waves; wave w: edge-tiles {2*(w&1), +1}, out-tiles {4*(w>>1)..+3}.
// Per k-step: reg-stage next weight slice (T14 split), 1 barrier, 2 A + 4 B b128, 8 MFMA.
__device__ __forceinline__ void gemm64(const short* As, int astride,
                                       const short* Wp, int nks,
                                       short* bkS, f32x4 acc[2][4], int t)
{
  const int lane = t & 63, w = t >> 6;
  const int q = lane >> 4, fr = lane & 15;
  const int erow = (w & 1) * 32;
  const int ocol = (w >> 1) * 64;
  const int4* g = reinterpret_cast<const int4*>(Wp);
  int4 p0 = g[t], p1 = g[256 + t];
  for (int ks = 0; ks < nks; ++ks){
    int4* bkw = reinterpret_cast<int4*>(bkS + (ks&1)*4096);
    bkw[t] = p0; bkw[256 + t] = p1;            // compiler inserts vmcnt wait on p0/p1
    __syncthreads();                           // slice ks staged; prev reads done
    if (ks + 1 < nks){ p0 = g[(ks+1)*512 + t]; p1 = g[(ks+1)*512 + 256 + t]; } // prefetch overlaps MFMA
    short8v a[2], b[4];
    #pragma unroll
    for (int et=0; et<2; ++et)
      a[et] = *reinterpret_cast<const short8v*>(As + (erow + et*16 + fr)*astride + ks*32 + q*8);
    #pragma unroll
    for (int ot=0; ot<4; ++ot)
      b[ot] = *reinterpret_cast<const short8v*>(bkS + (ks&1)*4096 + (ocol + ot*16 + fr)*32 + q*8);
    #pragma unroll
    for (int et=0; et<2; ++et)
      #pragma unroll
      for (int ot=0; ot<4; ++ot)
        acc[et][ot] = __builtin_amdgcn_mfma_f32_16x16x32_bf16(a[et], b[ot], acc[et][ot], 0, 0, 0);
  }
  __syncthreads();   // all waves done reading bk/As before caller's next phase
}

// acc -> silu(acc + bias) -> bf16 LDS tile [64][HST]
__device__ __forceinline__ void epilogue_store(const f32x4 acc[2][4], const float* bS,
                                               short* dst, int t)
{
  const int lane = t & 63, w = t >> 6;
  const int q = lane >> 4, fr = lane & 15;
  #pragma unroll
  for (int et=0; et<2; ++et){
    #pragma unroll
    for (int ot=0; ot<4; ++ot){
      int o = (w>>1)*64 + ot*16 + fr;
      float bv = bS[o];
      #pragma unroll
      for (int r=0;r<4;++r){
        int e = (w&1)*32 + et*16 + q*4 + r;
        dst[e*HST + o] = bfr(siluf(acc[et][ot][r] + bv));
      }
    }
  }
}

__global__ __launch_bounds__(256) void edge_mfma_kernel(
    const float* __restrict__ h, const float* __restrict__ x,
    const float* __restrict__ ea, const float* __restrict__ mask,
    const int* __restrict__ eidx,
    const short* __restrict__ W1p, const float* __restrict__ b1,
    const short* __restrict__ W2p, const float* __restrict__ b2,
    const float* __restrict__ Wg, const float* __restrict__ bg,
    const short* __restrict__ C1p, const float* __restrict__ bc1,
    const float* __restrict__ Wc2, const float* __restrict__ cb2,
    float* __restrict__ magg, float* __restrict__ xout)
{
  __shared__ __align__(16) short msgS[ME*MST];   // msg_in bf16; later m (stride HST)
  __shared__ __align__(16) short hidS[ME*HST];   // hidden1; later hidden2
  __shared__ __align__(16) short bkS[2*4096];    // weight k-slice double buffer
  __shared__ float b1S[HID], b2S[HID], bc1S[HID], wgS[HID], wc2S[HID];
  __shared__ float maskS[ME], scaleS[ME], cdS[ME][3];
  __shared__ int colS[ME];

  const int t = threadIdx.x;
  const int e0 = blockIdx.x * ME;

  if (t < HID){
    b1S[t] = b1[t]; b2S[t] = b2[t]; bc1S[t] = bc1[t];
    wgS[t] = Wg[t]; wc2S[t] = Wc2[t];
  }
  if (t < ME){
    int e = e0 + t;
    int r = eidx[e], c = eidx[NE + e];
    colS[t] = c; maskS[t] = mask[e];
    float dx = x[c*3+0]-x[r*3+0];
    float dy = x[c*3+1]-x[r*3+1];
    float dz = x[c*3+2]-x[r*3+2];
    cdS[t][0]=dx; cdS[t][1]=dy; cdS[t][2]=dz;
    msgS[t*MST + 256] = bfr(sqrtf(dx*dx+dy*dy+dz*dz));
    #pragma unroll
    for (int j=0;j<4;++j) msgS[t*MST + 257 + j] = bfr(ea[(size_t)e*4 + j]);
    for (int k=DIN;k<MST;++k) msgS[t*MST + k] = 0;   // zero K-pad (read by last k-step)
  }
  // gather h[col], h[row] -> bf16 msg tile (4 threads per edge, 32 chans each)
  {
    int e = t >> 2, seg = t & 3;
    int ge = e0 + e;
    int r = eidx[ge], c = eidx[NE + ge];
    const float4* hc = reinterpret_cast<const float4*>(h + (size_t)c*HID + seg*32);
    const float4* hr = reinterpret_cast<const float4*>(h + (size_t)r*HID + seg*32);
    #pragma unroll
    for (int bq=0;bq<4;++bq){
      float4 u = hc[bq*2], v = hc[bq*2+1];
      short8v s;
      s[0]=bfr(u.x); s[1]=bfr(u.y); s[2]=bfr(u.z); s[3]=bfr(u.w);
      s[4]=bfr(v.x); s[5]=bfr(v.y); s[6]=bfr(v.z); s[7]=bfr(v.w);
      *reinterpret_cast<short8v*>(&msgS[e*MST + seg*32 + bq*8]) = s;
      float4 u2 = hr[bq*2], v2 = hr[bq*2+1];
      short8v s2;
      s2[0]=bfr(u2.x); s2[1]=bfr(u2.y); s2[2]=bfr(u2.z); s2[3]=bfr(u2.w);
      s2[4]=bfr(v2.x); s2[5]=bfr(v2.y); s2[6]=bfr(v2.z); s2[7]=bfr(v2.w);
      *reinterpret_cast<short8v*>(&msgS[e*MST + 128 + seg*32 + bq*8]) = s2;
    }
  }
  // (gemm64's first loop-top barrier publishes the msg tile)

  f32x4 z = {0.f,0.f,0.f,0.f};
  f32x4 acc1[2][4];
  #pragma unroll
  for (int i=0;i<2;++i){ acc1[i][0]=z; acc1[i][1]=z; acc1[i][2]=z; acc1[i][3]=z; }
  gemm64(msgS, MST, W1p, NKS1, bkS, acc1, t);
  epilogue_store(acc1, b1S, hidS, t);              // hidden1

  f32x4 acc2[2][4];
  #pragma unroll
  for (int i=0;i<2;++i){ acc2[i][0]=z; acc2[i][1]=z; acc2[i][2]=z; acc2[i][3]=z; }
  gemm64(hidS, HST, W2p, NKS2, bkS, acc2, t);
  epilogue_store(acc2, b2S, msgS, t);              // m_pre (msg buffer reused, stride HST)
  __syncthreads();

  // gate = sigmoid(m_pre . Wg + bg) * mask   (4 threads per edge)
  {
    int e = t >> 2, g = t & 3;
    float p = 0.f;
    #pragma unroll
    for (int bq=0;bq<4;++bq){
      short8v s = *reinterpret_cast<const short8v*>(&msgS[e*HST + g*32 + bq*8]);
      #pragma unroll
      for (int j=0;j<8;++j) p += bf2f(s[j]) * wgS[g*32 + bq*8 + j];
    }
    p += __shfl_xor(p, 1); p += __shfl_xor(p, 2);
    if (g == 0) scaleS[e] = sigf(p + bg[0]) * maskS[e];
  }
  __syncthreads();

  // m = m_pre * gate * mask; scatter to m_aggr[col]
  {
    int o = t & 127, halfe = t >> 7;
    #pragma unroll 4
    for (int i=0;i<32;++i){
      int e = halfe*32 + i;
      int idx = e*HST + o;
      float v = bf2f(msgS[idx]) * scaleS[e];
      msgS[idx] = bfr(v);
      atomicAdd(&magg[(size_t)colS[e]*HID + o], v);
    }
  }
  // (gemm64's loop-top barrier publishes scaled m)

  f32x4 acc3[2][4];
  #pragma unroll
  for (int i=0;i<2;++i){ acc3[i][0]=z; acc3[i][1]=z; acc3[i][2]=z; acc3[i][3]=z; }
  gemm64(msgS, HST, C1p, NKS2, bkS, acc3, t);
  epilogue_store(acc3, bc1S, hidS, t);             // hidden2
  __syncthreads();

  // cw = hidden2 . Wc2 + cb2 ; x_out[col] += coord_diff * cw
  {
    int e = t >> 2, g = t & 3;
    float p = 0.f;
    #pragma unroll
    for (int bq=0;bq<4;++bq){
      short8v s = *reinterpret_cast<const short8v*>(&hidS[e*HST + g*32 + bq*8]);
      #pragma unroll
      for (int j=0;j<8;++j) p += bf2f(s[j]) * wc2S[g*32 + bq*8 + j];
    }
    p += __shfl_xor(p, 1); p += __shfl_xor(p, 2);
    if (g == 0){
      float cw = p + cb2[0];
      int c = colS[e];
      atomicAdd(&xout[c*3+0], cdS[e][0]*cw);
      atomicAdd(&xout[c*3+1], cdS[e][1]*cw);
      atomicAdd(&xout[c*3+2], cdS[e][2]*cw);
    }
  }
}

// -------- node update (fp32, unchanged from R1) --------
__global__ __launch_bounds__(256) void node_kernel(
    float* __restrict__ h, const float* __restrict__ magg,
    const float* __restrict__ Wn1, const float* __restrict__ bn1,
    const float* __restrict__ Wn2, const float* __restrict__ bn2)
{
  __shared__ float inT[2*HID][TP];
  __shared__ float hidT[HID][TP];
  const int t  = threadIdx.x;
  const int n0 = blockIdx.x * TN;
  {
    int nl = t >> 4, sub = t & 15;
    int n = n0 + nl;
    const float* hp = h + (size_t)n*HID;
    const float* mp = magg + (size_t)n*HID;
    for (int i=sub;i<HID;i+=16){
      inT[i][nl]     = hp[i];
      inT[128+i][nl] = mp[i];
    }
  }
  __syncthreads();
  const int o  = t & 127;
  const int nb = (t >> 7) * 8;

  float acc[8];
  #pragma unroll
  for (int j=0;j<8;++j) acc[j] = bn1[o];
  #pragma unroll 4
  for (int i=0;i<2*HID;++i){
    float w = Wn1[i*HID+o];
    float4 a0 = *reinterpret_cast<const float4*>(&inT[i][nb]);
    float4 a1 = *reinterpret_cast<const float4*>(&inT[i][nb+4]);
    acc[0]=fmaf(a0.x,w,acc[0]); acc[1]=fmaf(a0.y,w,acc[1]);
    acc[2]=fmaf(a0.z,w,acc[2]); acc[3]=fmaf(a0.w,w,acc[3]);
    acc[4]=fmaf(a1.x,w,acc[4]); acc[5]=fmaf(a1.y,w,acc[5]);
    acc[6]=fmaf(a1.z,w,acc[6]); acc[7]=fmaf(a1.w,w,acc[7]);
  }
  #pragma unroll
  for (int j=0;j<8;++j) hidT[o][nb+j] = siluf(acc[j]);
  __syncthreads();

  float dh[8];
  #pragma unroll
  for (int j=0;j<8;++j) dh[j] = bn2[o];
  #pragma unroll 4
  for (int k=0;k<HID;++k){
    float w = Wn2[k*HID+o];
    float4 a0 = *reinterpret_cast<const float4*>(&hidT[k][nb]);
    float4 a1 = *reinterpret_cast<const float4*>(&hidT[k][nb+4]);
    dh[0]=fmaf(a0.x,w,dh[0]); dh[1]=fmaf(a0.y,w,dh[1]);
    dh[2]=fmaf(a0.z,w,dh[2]); dh[3]=fmaf(a0.w,w,dh[3]);
    dh[4]=fmaf(a1.x,w,dh[4]); dh[5]=fmaf(a1.y,w,dh[5]);
    dh[6]=fmaf(a1.z,w,dh[6]); dh[7]=fmaf(a1.w,w,dh[7]);
  }
  #pragma unroll
  for (int j=0;j<8;++j){
    int n = n0 + nb + j;
    h[(size_t)n*HID + o] = inT[o][nb+j] + dh[j];
  }
}

__global__ void pool_kernel(const float* __restrict__ h, const int* __restrict__ batch,
                            float* __restrict__ sums, float* __restrict__ counts){
  int o  = threadIdx.x;
  int n0 = blockIdx.x * 16;
  int curg = batch[n0];
  float accv = 0.f, cnt = 0.f;
  for (int j=0;j<16;++j){
    int n = n0 + j;
    int g = batch[n];
    if (g != curg){
      atomicAdd(&sums[(size_t)curg*HID+o], accv);
      if (o==0) atomicAdd(&counts[curg], cnt);
      accv = 0.f; cnt = 0.f; curg = g;
    }
    accv += h[(size_t)n*HID+o];
    cnt  += 1.f;
  }
  atomicAdd(&sums[(size_t)curg*HID+o], accv);
  if (o==0) atomicAdd(&counts[curg], cnt);
}

__global__ void out_kernel(const float* __restrict__ sums, const float* __restrict__ counts,
                           const float* __restrict__ rW, const float* __restrict__ rb,
                           float* __restrict__ out){
  int g = blockIdx.x; int t = threadIdx.x;  // 64 threads
  float v = sums[(size_t)g*HID + t]*rW[t] + sums[(size_t)g*HID + 64 + t]*rW[64+t];
  #pragma unroll
  for (int off=32; off>0; off>>=1) v += __shfl_down(v, off);
  if (t==0) out[g] = v / fmaxf(counts[g], 1.0f) + rb[0];
}

extern "C" void kernel_launch(void* const* d_in, const int* in_sizes, int n_in,
                              void* d_out, int out_size, void* d_ws, size_t ws_size,
                              hipStream_t stream)
{
  const float* x_feat = (const float*)d_in[0];
  const float* pos    = (const float*)d_in[1];
  const float* eattr  = (const float*)d_in[2];
  const float* p      = (const float*)d_in[3];
  const float* embW   = (const float*)d_in[4];
  const float* embB   = (const float*)d_in[5];
  const float* eW1    = (const float*)d_in[6];
  const float* eb1    = (const float*)d_in[7];
  const float* eW2    = (const float*)d_in[8];
  const float* eb2    = (const float*)d_in[9];
  const float* gW     = (const float*)d_in[10];
  const float* gb     = (const float*)d_in[11];
  const float* nW1    = (const float*)d_in[12];
  const float* nb1    = (const float*)d_in[13];
  const float* nW2    = (const float*)d_in[14];
  const float* nb2    = (const float*)d_in[15];
  const float* cW1    = (const float*)d_in[16];
  const float* cb1    = (const float*)d_in[17];
  const float* cW2    = (const float*)d_in[18];
  const float* cb2    = (const float*)d_in[19];
  const float* rW     = (const float*)d_in[20];
  const float* rb     = (const float*)d_in[21];
  const int* eidx     = (const int*)d_in[22];
  const int* einv     = (const int*)d_in[23];
  const int* batch    = (const int*)d_in[24];

  float* ws = (float*)d_ws;
  float* h      = ws;  ws += (size_t)NN*HID;
  float* magg   = ws;  ws += (size_t)NN*HID;
  float* xA     = ws;  ws += NN*3;
  float* xB     = ws;  ws += NN*3;
  float* mask   = ws;  ws += NE;
  float* sums   = ws;  ws += (size_t)NG*HID;
  float* counts = ws;  ws += NG;
  short* W1p = (short*)(ws);                           // [4][9][128][32] bf16
  short* W2p = W1p + (size_t)NL*NKS1*HID*32;           // [4][4][128][32]
  short* C1p = W2p + (size_t)NL*NKS2*HID*32;

  // prepack bf16 weights (runs every call; deterministic)
  prepack_kernel<<<(NL*NKS1*HID*32+255)/256, 256, 0, stream>>>(eW1, W1p, DIN, NKS1);
  prepack_kernel<<<(NL*NKS2*HID*32+255)/256, 256, 0, stream>>>(eW2, W2p, HID, NKS2);
  prepack_kernel<<<(NL*NKS2*HID*32+255)/256, 256, 0, stream>>>(cW1, C1p, HID, NKS2);

  hipMemcpyAsync(xA, pos, sizeof(float)*NN*3, hipMemcpyDeviceToDevice, stream);
  mask_kernel<<<(NE+255)/256, 256, 0, stream>>>(p, einv, mask);
  embed_kernel<<<NN, HID, 0, stream>>>(x_feat, embW, embB, h);

  float* xc = xA; float* xn = xB;
  for (int l=0;l<NL;++l){
    hipMemsetAsync(magg, 0, sizeof(float)*(size_t)NN*HID, stream);
    hipMemcpyAsync(xn, xc, sizeof(float)*NN*3, hipMemcpyDeviceToDevice, stream);
    edge_mfma_kernel<<<NE/ME, 256, 0, stream>>>(h, xc, eattr, mask, eidx,
        W1p + (size_t)l*NKS1*4096, eb1 + l*HID,
        W2p + (size_t)l*NKS2*4096, eb2 + l*HID,
        gW  + l*HID,               gb  + l,
        C1p + (size_t)l*NKS2*4096, cb1 + l*HID,
        cW2 + l*HID,               cb2 + l,
        magg, xn);
    node_kernel<<<NN/TN, 256, 0, stream>>>(h, magg,
        nW1 + (size_t)l*2*HID*HID, nb1 + l*HID,
        nW2 + (size_t)l*HID*HID,   nb2 + l*HID);
    float* tmp = xc; xc = xn; xn = tmp;
  }
  hipMemsetAsync(sums, 0, sizeof(float)*((size_t)NG*HID + NG), stream);
  pool_kernel<<<NN/16, HID, 0, stream>>>(h, batch, sums, counts);
  out_kernel<<<NG, 64, 0, stream>>>(sums, counts, rW, rb, (float*)d_out);
}

// Round 3
// 2849.059 us; speedup vs baseline: 2.9733x; 1.1163x over previous
//
#include <hip/hip_runtime.h>

#define NN 50000
#define NE 800000
#define HID 128
#define NG 2500
#define NL 4
#define DIN 261
#define NKS1 9      // ceil(261/32) k-steps for GEMM1
#define NKS2 4      // 128/32
#define ME 64       // edges per block
#define MST 296     // msg row stride (shorts)
#define HST 136     // hid/m row stride (shorts)
#define BST 40      // weight k-slice row stride (shorts): 80B -> bank stride 20, conflict-free
#define TN 16
#define TP 20

typedef __attribute__((ext_vector_type(8))) short short8v;
typedef __attribute__((ext_vector_type(4))) float f32x4;

__device__ __forceinline__ float sigf(float x){ return 1.0f/(1.0f+__expf(-x)); }
__device__ __forceinline__ float siluf(float x){ return x/(1.0f+__expf(-x)); }
__device__ __forceinline__ short bfr(float x){
  unsigned u = __float_as_uint(x);
  u += 0x7fffu + ((u>>16)&1u);
  return (short)(u>>16);
}
__device__ __forceinline__ float bf2f(short s){
  return __uint_as_float(((unsigned)(unsigned short)s)<<16);
}

// ---------------- counting sort of edges by col ----------------
__global__ void zero_hist(int* __restrict__ hist){
  int i = blockIdx.x*256 + threadIdx.x;
  if (i < NN) hist[i] = 0;
}
__global__ void hist_kernel(const int* __restrict__ eidx, int* __restrict__ hist){
  int e = blockIdx.x*256 + threadIdx.x;
  if (e < NE) atomicAdd(&hist[eidx[NE+e]], 1);
}
__global__ __launch_bounds__(1024) void scan_kernel(const int* __restrict__ hist,
                                                    int* __restrict__ cursor){
  __shared__ int part[1024];
  int t = threadIdx.x;
  const int CH = (NN + 1023)/1024;     // 49
  int base = t*CH;
  int s = 0;
  for (int j=0;j<CH;++j){ int i=base+j; if (i<NN) s += hist[i]; }
  part[t] = s; __syncthreads();
  for (int d=1; d<1024; d<<=1){
    int v = (t>=d) ? part[t-d] : 0;
    __syncthreads();
    part[t] += v;
    __syncthreads();
  }
  int ex = (t==0) ? 0 : part[t-1];
  for (int j=0;j<CH;++j){
    int i=base+j;
    if (i<NN){ cursor[i] = ex; ex += hist[i]; }
  }
}
__global__ void scatter_kernel(const int* __restrict__ eidx, int* __restrict__ cursor,
                               int* __restrict__ se){
  int e = blockIdx.x*256 + threadIdx.x;
  if (e < NE){
    int c = eidx[NE+e];
    int pos = atomicAdd(&cursor[c], 1);
    se[pos] = e;
  }
}

// ---------------- weight prepack: [L][K][128] f32 -> [L][ks][o=128][kk=32] bf16 ----
__global__ void prepack_kernel(const float* __restrict__ W, short* __restrict__ out,
                               int K, int nks){
  int idx = blockIdx.x*256 + threadIdx.x;
  int total = NL*nks*HID*32;
  if (idx >= total) return;
  int kk = idx & 31;
  int o  = (idx>>5) & 127;
  int lks = idx >> 12;
  int ks = lks % nks;
  int l  = lks / nks;
  int k = ks*32 + kk;
  float v = (k < K) ? W[((size_t)l*K + k)*HID + o] : 0.0f;
  out[idx] = bfr(v);
}

__global__ void mask_kernel(const float* __restrict__ p, const int* __restrict__ inv,
                            float* __restrict__ mask){
  int e = blockIdx.x*256 + threadIdx.x;
  if (e < NE) mask[e] = (p[inv[e]] >= 0.0f) ? 1.0f : 0.0f;
}

__global__ void embed_kernel(const float* __restrict__ xf, const float* __restrict__ W,
                             const float* __restrict__ b, float* __restrict__ h){
  int n = blockIdx.x; int o = threadIdx.x;
  float s = b[o];
  #pragma unroll
  for (int i=0;i<11;++i) s = fmaf(xf[n*11+i], W[i*HID+o], s);
  h[(size_t)n*HID+o] = s;
}

// ---------------- MFMA tile-GEMM: [64 x K] (LDS bf16) @ [K x 128] (prepacked) ------
__device__ __forceinline__ void gemm64(const short* As, int astride,
                                       const short* Wp, int nks,
                                       short* bkS, f32x4 acc[2][4], int t)
{
  const int lane = t & 63, w = t >> 6;
  const int q = lane >> 4, fr = lane & 15;
  const int erow = (w & 1) * 32;
  const int ocol = (w >> 1) * 64;
  const int r0 = t >> 2, c0 = t & 3;
  const int4* g = reinterpret_cast<const int4*>(Wp);
  int4 p0 = g[t], p1 = g[256 + t];
  for (int ks = 0; ks < nks; ++ks){
    int4* bkw = reinterpret_cast<int4*>(bkS + (ks&1)*5120);
    bkw[r0*5 + c0] = p0;
    bkw[(r0+64)*5 + c0] = p1;
    __syncthreads();
    if (ks + 1 < nks){ p0 = g[(ks+1)*512 + t]; p1 = g[(ks+1)*512 + 256 + t]; }
    short8v a[2], b[4];
    #pragma unroll
    for (int et=0; et<2; ++et)
      a[et] = *reinterpret_cast<const short8v*>(As + (erow + et*16 + fr)*astride + ks*32 + q*8);
    #pragma unroll
    for (int ot=0; ot<4; ++ot)
      b[ot] = *reinterpret_cast<const short8v*>(bkS + (ks&1)*5120 + (ocol + ot*16 + fr)*BST + q*8);
    #pragma unroll
    for (int et=0; et<2; ++et)
      #pragma unroll
      for (int ot=0; ot<4; ++ot)
        acc[et][ot] = __builtin_amdgcn_mfma_f32_16x16x32_bf16(a[et], b[ot], acc[et][ot], 0, 0, 0);
  }
  __syncthreads();
}

__device__ __forceinline__ void epilogue_store(const f32x4 acc[2][4], const float* bS,
                                               short* dst, int t)
{
  const int lane = t & 63, w = t >> 6;
  const int q = lane >> 4, fr = lane & 15;
  #pragma unroll
  for (int et=0; et<2; ++et){
    #pragma unroll
    for (int ot=0; ot<4; ++ot){
      int o = (w>>1)*64 + ot*16 + fr;
      float bv = bS[o];
      #pragma unroll
      for (int r=0;r<4;++r){
        int e = (w&1)*32 + et*16 + q*4 + r;
        dst[e*HST + o] = bfr(siluf(acc[et][ot][r] + bv));
      }
    }
  }
}

__global__ __launch_bounds__(256) void edge_mfma_kernel(
    const float* __restrict__ h, const float* __restrict__ x,
    const float* __restrict__ ea, const float* __restrict__ mask,
    const int* __restrict__ eidx, const int* __restrict__ se,
    const short* __restrict__ W1p, const float* __restrict__ b1,
    const short* __restrict__ W2p, const float* __restrict__ b2,
    const float* __restrict__ Wg, const float* __restrict__ bg,
    const short* __restrict__ C1p, const float* __restrict__ bc1,
    const float* __restrict__ Wc2, const float* __restrict__ cb2,
    float* __restrict__ magg, float* __restrict__ xout)
{
  __shared__ __align__(16) short msgS[ME*MST];
  __shared__ __align__(16) short hidS[ME*HST];
  __shared__ __align__(16) short bkS[2*5120];
  __shared__ float b1S[HID], b2S[HID], bc1S[HID], wgS[HID], wc2S[HID];
  __shared__ float maskS[ME], scaleS[ME], cwS[ME], cdS[ME][3];
  __shared__ int colS[ME];

  const int t = threadIdx.x;
  const int i0g = blockIdx.x * ME;

  if (t < HID){
    b1S[t] = b1[t]; b2S[t] = b2[t]; bc1S[t] = bc1[t];
    wgS[t] = Wg[t]; wc2S[t] = Wc2[t];
  }
  if (t < ME){
    int e = se[i0g + t];
    int r = eidx[e], c = eidx[NE + e];
    colS[t] = c; maskS[t] = mask[e];
    float dx = x[c*3+0]-x[r*3+0];
    float dy = x[c*3+1]-x[r*3+1];
    float dz = x[c*3+2]-x[r*3+2];
    cdS[t][0]=dx; cdS[t][1]=dy; cdS[t][2]=dz;
    msgS[t*MST + 256] = bfr(sqrtf(dx*dx+dy*dy+dz*dz));
    #pragma unroll
    for (int j=0;j<4;++j) msgS[t*MST + 257 + j] = bfr(ea[(size_t)e*4 + j]);
    for (int k=DIN;k<MST;++k) msgS[t*MST + k] = 0;
  }
  // gather h[col], h[row] -> bf16 msg tile (4 threads per edge)
  {
    int el = t >> 2, seg = t & 3;
    int e = se[i0g + el];
    int r = eidx[e], c = eidx[NE + e];
    const float4* hc = reinterpret_cast<const float4*>(h + (size_t)c*HID + seg*32);
    const float4* hr = reinterpret_cast<const float4*>(h + (size_t)r*HID + seg*32);
    #pragma unroll
    for (int bq=0;bq<4;++bq){
      float4 u = hc[bq*2], v = hc[bq*2+1];
      short8v s;
      s[0]=bfr(u.x); s[1]=bfr(u.y); s[2]=bfr(u.z); s[3]=bfr(u.w);
      s[4]=bfr(v.x); s[5]=bfr(v.y); s[6]=bfr(v.z); s[7]=bfr(v.w);
      *reinterpret_cast<short8v*>(&msgS[el*MST + seg*32 + bq*8]) = s;
      float4 u2 = hr[bq*2], v2 = hr[bq*2+1];
      short8v s2;
      s2[0]=bfr(u2.x); s2[1]=bfr(u2.y); s2[2]=bfr(u2.z); s2[3]=bfr(u2.w);
      s2[4]=bfr(v2.x); s2[5]=bfr(v2.y); s2[6]=bfr(v2.z); s2[7]=bfr(v2.w);
      *reinterpret_cast<short8v*>(&msgS[el*MST + 128 + seg*32 + bq*8]) = s2;
    }
  }

  f32x4 z = {0.f,0.f,0.f,0.f};
  f32x4 acc1[2][4];
  #pragma unroll
  for (int i=0;i<2;++i){ acc1[i][0]=z; acc1[i][1]=z; acc1[i][2]=z; acc1[i][3]=z; }
  gemm64(msgS, MST, W1p, NKS1, bkS, acc1, t);
  epilogue_store(acc1, b1S, hidS, t);
  __syncthreads();

  f32x4 acc2[2][4];
  #pragma unroll
  for (int i=0;i<2;++i){ acc2[i][0]=z; acc2[i][1]=z; acc2[i][2]=z; acc2[i][3]=z; }
  gemm64(hidS, HST, W2p, NKS2, bkS, acc2, t);
  epilogue_store(acc2, b2S, msgS, t);              // m_pre, stride HST
  __syncthreads();

  // gate = sigmoid(m_pre . Wg + bg) * mask   (4 threads per edge)
  {
    int e = t >> 2, g = t & 3;
    float p = 0.f;
    #pragma unroll
    for (int bq=0;bq<4;++bq){
      short8v s = *reinterpret_cast<const short8v*>(&msgS[e*HST + g*32 + bq*8]);
      #pragma unroll
      for (int j=0;j<8;++j) p += bf2f(s[j]) * wgS[g*32 + bq*8 + j];
    }
    p += __shfl_xor(p, 1); p += __shfl_xor(p, 2);
    if (g == 0) scaleS[e] = sigf(p + bg[0]) * maskS[e];
  }
  __syncthreads();

  // m = m_pre * gate * mask; segmented-scan aggregate into magg (cols sorted)
  {
    int o = t & 127, half = t >> 7;
    int ib = half*32;
    float accv = 0.f;
    int curc = colS[ib];
    #pragma unroll 4
    for (int j=0;j<32;++j){
      int i = ib + j;
      int c = colS[i];
      if (c != curc){
        atomicAdd(&magg[(size_t)curc*HID + o], accv);
        accv = 0.f; curc = c;
      }
      int idx = i*HST + o;
      float v = bf2f(msgS[idx]) * scaleS[i];
      msgS[idx] = bfr(v);
      accv += v;
    }
    atomicAdd(&magg[(size_t)curc*HID + o], accv);
  }
  __syncthreads();

  f32x4 acc3[2][4];
  #pragma unroll
  for (int i=0;i<2;++i){ acc3[i][0]=z; acc3[i][1]=z; acc3[i][2]=z; acc3[i][3]=z; }
  gemm64(msgS, HST, C1p, NKS2, bkS, acc3, t);
  epilogue_store(acc3, bc1S, hidS, t);
  __syncthreads();

  // cw = hidden2 . Wc2 + cb2
  {
    int e = t >> 2, g = t & 3;
    float p = 0.f;
    #pragma unroll
    for (int bq=0;bq<4;++bq){
      short8v s = *reinterpret_cast<const short8v*>(&hidS[e*HST + g*32 + bq*8]);
      #pragma unroll
      for (int j=0;j<8;++j) p += bf2f(s[j]) * wc2S[g*32 + bq*8 + j];
    }
    p += __shfl_xor(p, 1); p += __shfl_xor(p, 2);
    if (g == 0) cwS[e] = p + cb2[0];
  }
  __syncthreads();

  // x_out[col] += coord_diff * cw, segmented by sorted col
  if (t < 6){
    int d = t % 3, half = t / 3;
    int ib = half*32;
    float accx = 0.f;
    int curc = colS[ib];
    for (int j=0;j<32;++j){
      int i = ib + j;
      int c = colS[i];
      if (c != curc){
        atomicAdd(&xout[curc*3+d], accx);
        accx = 0.f; curc = c;
      }
      accx += cdS[i][d] * cwS[i];
    }
    atomicAdd(&xout[curc*3+d], accx);
  }
}

// -------- node update (fp32) --------
__global__ __launch_bounds__(256) void node_kernel(
    float* __restrict__ h, const float* __restrict__ magg,
    const float* __restrict__ Wn1, const float* __restrict__ bn1,
    const float* __restrict__ Wn2, const float* __restrict__ bn2)
{
  __shared__ float inT[2*HID][TP];
  __shared__ float hidT[HID][TP];
  const int t  = threadIdx.x;
  const int n0 = blockIdx.x * TN;
  {
    int nl = t >> 4, sub = t & 15;
    int n = n0 + nl;
    const float* hp = h + (size_t)n*HID;
    const float* mp = magg + (size_t)n*HID;
    for (int i=sub;i<HID;i+=16){
      inT[i][nl]     = hp[i];
      inT[128+i][nl] = mp[i];
    }
  }
  __syncthreads();
  const int o  = t & 127;
  const int nb = (t >> 7) * 8;

  float acc[8];
  #pragma unroll
  for (int j=0;j<8;++j) acc[j] = bn1[o];
  #pragma unroll 4
  for (int i=0;i<2*HID;++i){
    float w = Wn1[i*HID+o];
    float4 a0 = *reinterpret_cast<const float4*>(&inT[i][nb]);
    float4 a1 = *reinterpret_cast<const float4*>(&inT[i][nb+4]);
    acc[0]=fmaf(a0.x,w,acc[0]); acc[1]=fmaf(a0.y,w,acc[1]);
    acc[2]=fmaf(a0.z,w,acc[2]); acc[3]=fmaf(a0.w,w,acc[3]);
    acc[4]=fmaf(a1.x,w,acc[4]); acc[5]=fmaf(a1.y,w,acc[5]);
    acc[6]=fmaf(a1.z,w,acc[6]); acc[7]=fmaf(a1.w,w,acc[7]);
  }
  #pragma unroll
  for (int j=0;j<8;++j) hidT[o][nb+j] = siluf(acc[j]);
  __syncthreads();

  float dh[8];
  #pragma unroll
  for (int j=0;j<8;++j) dh[j] = bn2[o];
  #pragma unroll 4
  for (int k=0;k<HID;++k){
    float w = Wn2[k*HID+o];
    float4 a0 = *reinterpret_cast<const float4*>(&hidT[k][nb]);
    float4 a1 = *reinterpret_cast<const float4*>(&hidT[k][nb+4]);
    dh[0]=fmaf(a0.x,w,dh[0]); dh[1]=fmaf(a0.y,w,dh[1]);
    dh[2]=fmaf(a0.z,w,dh[2]); dh[3]=fmaf(a0.w,w,dh[3]);
    dh[4]=fmaf(a1.x,w,dh[4]); dh[5]=fmaf(a1.y,w,dh[5]);
    dh[6]=fmaf(a1.z,w,dh[6]); dh[7]=fmaf(a1.w,w,dh[7]);
  }
  #pragma unroll
  for (int j=0;j<8;++j){
    int n = n0 + nb + j;
    h[(size_t)n*HID + o] = inT[o][nb+j] + dh[j];
  }
}

__global__ void pool_kernel(const float* __restrict__ h, const int* __restrict__ batch,
                            float* __restrict__ sums, float* __restrict__ counts){
  int o  = threadIdx.x;
  int n0 = blockIdx.x * 16;
  int curg = batch[n0];
  float accv = 0.f, cnt = 0.f;
  for (int j=0;j<16;++j){
    int n = n0 + j;
    int g = batch[n];
    if (g != curg){
      atomicAdd(&sums[(size_t)curg*HID+o], accv);
      if (o==0) atomicAdd(&counts[curg], cnt);
      accv = 0.f; cnt = 0.f; curg = g;
    }
    accv += h[(size_t)n*HID+o];
    cnt  += 1.f;
  }
  atomicAdd(&sums[(size_t)curg*HID+o], accv);
  if (o==0) atomicAdd(&counts[curg], cnt);
}

__global__ void out_kernel(const float* __restrict__ sums, const float* __restrict__ counts,
                           const float* __restrict__ rW, const float* __restrict__ rb,
                           float* __restrict__ out){
  int g = blockIdx.x; int t = threadIdx.x;
  float v = sums[(size_t)g*HID + t]*rW[t] + sums[(size_t)g*HID + 64 + t]*rW[64+t];
  #pragma unroll
  for (int off=32; off>0; off>>=1) v += __shfl_down(v, off);
  if (t==0) out[g] = v / fmaxf(counts[g], 1.0f) + rb[0];
}

extern "C" void kernel_launch(void* const* d_in, const int* in_sizes, int n_in,
                              void* d_out, int out_size, void* d_ws, size_t ws_size,
                              hipStream_t stream)
{
  const float* x_feat = (const float*)d_in[0];
  const float* pos    = (const float*)d_in[1];
  const float* eattr  = (const float*)d_in[2];
  const float* p      = (const float*)d_in[3];
  const float* embW   = (const float*)d_in[4];
  const float* embB   = (const float*)d_in[5];
  const float* eW1    = (const float*)d_in[6];
  const float* eb1    = (const float*)d_in[7];
  const float* eW2    = (const float*)d_in[8];
  const float* eb2    = (const float*)d_in[9];
  const float* gW     = (const float*)d_in[10];
  const float* gb     = (const float*)d_in[11];
  const float* nW1    = (const float*)d_in[12];
  const float* nb1    = (const float*)d_in[13];
  const float* nW2    = (const float*)d_in[14];
  const float* nb2    = (const float*)d_in[15];
  const float* cW1    = (const float*)d_in[16];
  const float* cb1    = (const float*)d_in[17];
  const float* cW2    = (const float*)d_in[18];
  const float* cb2    = (const float*)d_in[19];
  const float* rW     = (const float*)d_in[20];
  const float* rb     = (const float*)d_in[21];
  const int* eidx     = (const int*)d_in[22];
  const int* einv     = (const int*)d_in[23];
  const int* batch    = (const int*)d_in[24];

  float* ws = (float*)d_ws;
  float* h      = ws;  ws += (size_t)NN*HID;
  float* magg   = ws;  ws += (size_t)NN*HID;
  float* xA     = ws;  ws += NN*3;
  float* xB     = ws;  ws += NN*3;
  float* mask   = ws;  ws += NE;
  float* sums   = ws;  ws += (size_t)NG*HID;
  float* counts = ws;  ws += NG;
  int*   hist   = (int*)ws;  ws += NN;      // doubles as scan cursor
  int*   se     = (int*)ws;  ws += NE;
  short* W1p = (short*)(ws);
  short* W2p = W1p + (size_t)NL*NKS1*HID*32;
  short* C1p = W2p + (size_t)NL*NKS2*HID*32;

  // counting sort of edges by col
  zero_hist<<<(NN+255)/256, 256, 0, stream>>>(hist);
  hist_kernel<<<(NE+255)/256, 256, 0, stream>>>(eidx, hist);
  scan_kernel<<<1, 1024, 0, stream>>>(hist, hist);   // in-place: hist -> cursor
  scatter_kernel<<<(NE+255)/256, 256, 0, stream>>>(eidx, hist, se);

  // prepack bf16 weights
  prepack_kernel<<<(NL*NKS1*HID*32+255)/256, 256, 0, stream>>>(eW1, W1p, DIN, NKS1);
  prepack_kernel<<<(NL*NKS2*HID*32+255)/256, 256, 0, stream>>>(eW2, W2p, HID, NKS2);
  prepack_kernel<<<(NL*NKS2*HID*32+255)/256, 256, 0, stream>>>(cW1, C1p, HID, NKS2);

  hipMemcpyAsync(xA, pos, sizeof(float)*NN*3, hipMemcpyDeviceToDevice, stream);
  mask_kernel<<<(NE+255)/256, 256, 0, stream>>>(p, einv, mask);
  embed_kernel<<<NN, HID, 0, stream>>>(x_feat, embW, embB, h);

  float* xc = xA; float* xn = xB;
  for (int l=0;l<NL;++l){
    hipMemsetAsync(magg, 0, sizeof(float)*(size_t)NN*HID, stream);
    hipMemcpyAsync(xn, xc, sizeof(float)*NN*3, hipMemcpyDeviceToDevice, stream);
    edge_mfma_kernel<<<NE/ME, 256, 0, stream>>>(h, xc, eattr, mask, eidx, se,
        W1p + (size_t)l*NKS1*4096, eb1 + l*HID,
        W2p + (size_t)l*NKS2*4096, eb2 + l*HID,
        gW  + l*HID,               gb  + l,
        C1p + (size_t)l*NKS2*4096, cb1 + l*HID,
        cW2 + l*HID,               cb2 + l,
        magg, xn);
    node_kernel<<<NN/TN, 256, 0, stream>>>(h, magg,
        nW1 + (size_t)l*2*HID*HID, nb1 + l*HID,
        nW2 + (size_t)l*HID*HID,   nb2 + l*HID);
    float* tmp = xc; xc = xn; xn = tmp;
  }
  hipMemsetAsync(sums, 0, sizeof(float)*((size_t)NG*HID + NG), stream);
  pool_kernel<<<NN/16, HID, 0, stream>>>(h, batch, sums, counts);
  out_kernel<<<NG, 64, 0, stream>>>(sums, counts, rW, rb, (float*)d_out);
}

// Round 4
// 2121.988 us; speedup vs baseline: 3.9921x; 1.3426x over previous
//
#include <hip/hip_runtime.h>

#define NN 50000
#define NE 800000
#define HID 128
#define NG 2500
#define NL 4
#define ME 64       // edges (or nodes) per block
#define HST 136     // LDS tile row stride (shorts): 272B -> 2-way max on b128
#define BST 40      // weight k-slice row stride (shorts)
#define NPB 782     // node blocks: ceil(50000/64)

typedef __attribute__((ext_vector_type(8))) short short8v;
typedef __attribute__((ext_vector_type(4))) float f32x4;

__device__ __forceinline__ float sigf(float x){ return 1.0f/(1.0f+__expf(-x)); }
__device__ __forceinline__ float siluf(float x){ return x/(1.0f+__expf(-x)); }
__device__ __forceinline__ short bfr(float x){
  unsigned u = __float_as_uint(x);
  u += 0x7fffu + ((u>>16)&1u);
  return (short)(u>>16);
}
__device__ __forceinline__ float bf2f(short s){
  return __uint_as_float(((unsigned)(unsigned short)s)<<16);
}

// ---------------- counting sort of edges by col ----------------
__global__ void zero_hist(int* __restrict__ hist){
  int i = blockIdx.x*256 + threadIdx.x;
  if (i < NN) hist[i] = 0;
}
__global__ void hist_kernel(const int* __restrict__ eidx, int* __restrict__ hist){
  int e = blockIdx.x*256 + threadIdx.x;
  if (e < NE) atomicAdd(&hist[eidx[NE+e]], 1);
}
__global__ __launch_bounds__(1024) void scan_kernel(const int* __restrict__ hist,
                                                    int* __restrict__ cursor){
  __shared__ int part[1024];
  int t = threadIdx.x;
  const int CH = (NN + 1023)/1024;
  int base = t*CH;
  int s = 0;
  for (int j=0;j<CH;++j){ int i=base+j; if (i<NN) s += hist[i]; }
  part[t] = s; __syncthreads();
  for (int d=1; d<1024; d<<=1){
    int v = (t>=d) ? part[t-d] : 0;
    __syncthreads();
    part[t] += v;
    __syncthreads();
  }
  int ex = (t==0) ? 0 : part[t-1];
  for (int j=0;j<CH;++j){
    int i=base+j;
    if (i<NN){ cursor[i] = ex; ex += hist[i]; }
  }
}
__global__ void scatter_kernel(const int* __restrict__ eidx, int* __restrict__ cursor,
                               int* __restrict__ se){
  int e = blockIdx.x*256 + threadIdx.x;
  if (e < NE){
    int c = eidx[NE+e];
    int pos = atomicAdd(&cursor[c], 1);
    se[pos] = e;
  }
}

// ---- weight prepack: rows [roff, roff+128) of [L][Ktot][128] -> [L][ks=4][o=128][kk=32] bf16
__global__ void prepack_kernel(const float* __restrict__ W, short* __restrict__ out,
                               int Ktot, int roff){
  int idx = blockIdx.x*256 + threadIdx.x;
  if (idx >= NL*4*HID*32) return;
  int kk = idx & 31;
  int o  = (idx>>5) & 127;
  int lks = idx >> 12;
  int ks = lks & 3;
  int l  = lks >> 2;
  int k = roff + ks*32 + kk;
  float v = (k < Ktot) ? W[((size_t)l*Ktot + k)*HID + o] : 0.0f;
  out[idx] = bfr(v);
}

__global__ void mask_kernel(const float* __restrict__ p, const int* __restrict__ inv,
                            float* __restrict__ mask){
  int e = blockIdx.x*256 + threadIdx.x;
  if (e < NE) mask[e] = (p[inv[e]] >= 0.0f) ? 1.0f : 0.0f;
}

__global__ void embed_kernel(const float* __restrict__ xf, const float* __restrict__ W,
                             const float* __restrict__ b, float* __restrict__ h){
  int n = blockIdx.x; int o = threadIdx.x;
  float s = b[o];
  #pragma unroll
  for (int i=0;i<11;++i) s = fmaf(xf[n*11+i], W[i*HID+o], s);
  h[(size_t)n*HID+o] = s;
}

// ---------------- MFMA tile-GEMM: [64 x 128] (LDS bf16) @ [128 x 128] (prepacked) ----
__device__ __forceinline__ void gemm64(const short* As, int astride,
                                       const short* Wp, int nks,
                                       short* bkS, f32x4 acc[2][4], int t)
{
  const int lane = t & 63, w = t >> 6;
  const int q = lane >> 4, fr = lane & 15;
  const int erow = (w & 1) * 32;
  const int ocol = (w >> 1) * 64;
  const int r0 = t >> 2, c0 = t & 3;
  const int4* g = reinterpret_cast<const int4*>(Wp);
  int4 p0 = g[t], p1 = g[256 + t];
  for (int ks = 0; ks < nks; ++ks){
    int4* bkw = reinterpret_cast<int4*>(bkS + (ks&1)*5120);
    bkw[r0*5 + c0] = p0;
    bkw[(r0+64)*5 + c0] = p1;
    __syncthreads();
    if (ks + 1 < nks){ p0 = g[(ks+1)*512 + t]; p1 = g[(ks+1)*512 + 256 + t]; }
    short8v a[2], b[4];
    #pragma unroll
    for (int et=0; et<2; ++et)
      a[et] = *reinterpret_cast<const short8v*>(As + (erow + et*16 + fr)*astride + ks*32 + q*8);
    #pragma unroll
    for (int ot=0; ot<4; ++ot)
      b[ot] = *reinterpret_cast<const short8v*>(bkS + (ks&1)*5120 + (ocol + ot*16 + fr)*BST + q*8);
    #pragma unroll
    for (int et=0; et<2; ++et)
      #pragma unroll
      for (int ot=0; ot<4; ++ot)
        acc[et][ot] = __builtin_amdgcn_mfma_f32_16x16x32_bf16(a[et], b[ot], acc[et][ot], 0, 0, 0);
  }
  __syncthreads();
}

// acc -> silu(acc + bias) -> bf16 LDS tile [64][HST]
__device__ __forceinline__ void epilogue_store(const f32x4 acc[2][4], const float* bS,
                                               short* dst, int t)
{
  const int lane = t & 63, w = t >> 6;
  const int q = lane >> 4, fr = lane & 15;
  #pragma unroll
  for (int et=0; et<2; ++et){
    #pragma unroll
    for (int ot=0; ot<4; ++ot){
      int o = (w>>1)*64 + ot*16 + fr;
      float bv = bS[o];
      #pragma unroll
      for (int r=0;r<4;++r){
        int e = (w&1)*32 + et*16 + q*4 + r;
        dst[e*HST + o] = bfr(siluf(acc[et][ot][r] + bv));
      }
    }
  }
}

// ---------------- per-layer node projections: A = bf16(h@W1hc + b1), B = bf16(h@W1hr) ----
__global__ __launch_bounds__(256) void nodeproj_kernel(
    const float* __restrict__ h,
    const short* __restrict__ Wcp, const float* __restrict__ b1,
    const short* __restrict__ Wrp,
    short* __restrict__ A, short* __restrict__ B)
{
  __shared__ __align__(16) short hT[ME*HST];
  __shared__ __align__(16) short bkS[2*5120];
  __shared__ float b1S[HID];
  const int t = threadIdx.x;
  const int n0 = blockIdx.x * ME;
  if (t < HID) b1S[t] = b1[t];
  {
    int nl = t >> 2, seg = t & 3;
    int n = n0 + nl; if (n >= NN) n = NN-1;
    const float4* hp = reinterpret_cast<const float4*>(h + (size_t)n*HID + seg*32);
    #pragma unroll
    for (int bq=0;bq<4;++bq){
      float4 u = hp[bq*2], v = hp[bq*2+1];
      short8v s;
      s[0]=bfr(u.x); s[1]=bfr(u.y); s[2]=bfr(u.z); s[3]=bfr(u.w);
      s[4]=bfr(v.x); s[5]=bfr(v.y); s[6]=bfr(v.z); s[7]=bfr(v.w);
      *reinterpret_cast<short8v*>(&hT[nl*HST + seg*32 + bq*8]) = s;
    }
  }
  f32x4 z = {0.f,0.f,0.f,0.f};
  f32x4 accA[2][4], accB[2][4];
  #pragma unroll
  for (int i=0;i<2;++i){ accA[i][0]=z;accA[i][1]=z;accA[i][2]=z;accA[i][3]=z;
                         accB[i][0]=z;accB[i][1]=z;accB[i][2]=z;accB[i][3]=z; }
  gemm64(hT, HST, Wcp, 4, bkS, accA, t);
  gemm64(hT, HST, Wrp, 4, bkS, accB, t);
  const int lane = t & 63, w = t >> 6;
  const int q = lane >> 4, fr = lane & 15;
  #pragma unroll
  for (int et=0; et<2; ++et){
    #pragma unroll
    for (int ot=0; ot<4; ++ot){
      int o = (w>>1)*64 + ot*16 + fr;
      float bv = b1S[o];
      #pragma unroll
      for (int r=0;r<4;++r){
        int e = (w&1)*32 + et*16 + q*4 + r;
        int n = n0 + e;
        if (n < NN){
          A[(size_t)n*HID + o] = bfr(accA[et][ot][r] + bv);
          B[(size_t)n*HID + o] = bfr(accB[et][ot][r]);
        }
      }
    }
  }
}

// ---------------- edge kernel: elementwise hidden1, then 2 MFMA GEMMs ----------------
__global__ __launch_bounds__(256) void edge2_kernel(
    const short* __restrict__ A, const short* __restrict__ B,
    const float* __restrict__ x, const float* __restrict__ ea,
    const float* __restrict__ mask,
    const int* __restrict__ eidx, const int* __restrict__ se,
    const float* __restrict__ wrow,   // eW1 + l*261*128 : rows 256..260 = wd, wea
    const short* __restrict__ W2p, const float* __restrict__ b2,
    const float* __restrict__ Wg, const float* __restrict__ bg,
    const short* __restrict__ C1p, const float* __restrict__ bc1,
    const float* __restrict__ Wc2, const float* __restrict__ cb2,
    float* __restrict__ magg, float* __restrict__ xout)
{
  __shared__ __align__(16) short hidS[ME*HST];   // hidden1, later hidden2
  __shared__ __align__(16) short mS[ME*HST];     // m_pre / m
  __shared__ __align__(16) short bkS[2*5120];
  __shared__ float b2S[HID], bc1S[HID], wgS[HID], wc2S[HID], wdS[HID];
  __shared__ float weaS[4][HID];
  __shared__ float maskS[ME], scaleS[ME], cwS[ME], distS[ME], cdS[ME][3];
  __shared__ int colS[ME];

  const int t = threadIdx.x;
  const int i0 = blockIdx.x * ME;

  // issue per-thread gathers early (4 threads/edge, 32 channels each)
  const int el = t >> 2, seg = t & 3;
  const int e = se[i0 + el];
  const int r = eidx[e], c = eidx[NE + e];
  const int4* Ap = reinterpret_cast<const int4*>(A + (size_t)c*HID + seg*32);
  const int4* Bp = reinterpret_cast<const int4*>(B + (size_t)r*HID + seg*32);
  int4 av0=Ap[0], av1=Ap[1], av2=Ap[2], av3=Ap[3];
  int4 bv0=Bp[0], bv1=Bp[1], bv2=Bp[2], bv3=Bp[3];
  float4 eav = *reinterpret_cast<const float4*>(ea + (size_t)e*4);

  if (t < HID){
    b2S[t] = b2[t]; bc1S[t] = bc1[t]; wgS[t] = Wg[t]; wc2S[t] = Wc2[t];
    wdS[t] = wrow[256*HID + t];
    #pragma unroll
    for (int j=0;j<4;++j) weaS[j][t] = wrow[(257+j)*HID + t];
  }
  if (t < ME){
    int e2 = se[i0 + t];
    int r2 = eidx[e2], c2 = eidx[NE + e2];
    colS[t] = c2; maskS[t] = mask[e2];
    float dx = x[c2*3+0]-x[r2*3+0];
    float dy = x[c2*3+1]-x[r2*3+1];
    float dz = x[c2*3+2]-x[r2*3+2];
    cdS[t][0]=dx; cdS[t][1]=dy; cdS[t][2]=dz;
    distS[t] = sqrtf(dx*dx+dy*dy+dz*dz);
  }
  __syncthreads();

  // hidden1 = silu(A[col] + B[row] + dist*wd + ea@wea)
  {
    float de = distS[el];
    const int4 avs[4] = {av0,av1,av2,av3};
    const int4 bvs[4] = {bv0,bv1,bv2,bv3};
    #pragma unroll
    for (int bq=0;bq<4;++bq){
      short8v a8 = *reinterpret_cast<const short8v*>(&avs[bq]);
      short8v b8 = *reinterpret_cast<const short8v*>(&bvs[bq]);
      short8v s;
      #pragma unroll
      for (int j=0;j<8;++j){
        int o = seg*32 + bq*8 + j;
        float v = bf2f(a8[j]) + bf2f(b8[j]) + de*wdS[o]
                + eav.x*weaS[0][o] + eav.y*weaS[1][o]
                + eav.z*weaS[2][o] + eav.w*weaS[3][o];
        s[j] = bfr(siluf(v));
      }
      *reinterpret_cast<short8v*>(&hidS[el*HST + seg*32 + bq*8]) = s;
    }
  }
  // gemm64's loop-top barrier publishes hidS

  f32x4 z = {0.f,0.f,0.f,0.f};
  f32x4 acc2[2][4];
  #pragma unroll
  for (int i=0;i<2;++i){ acc2[i][0]=z; acc2[i][1]=z; acc2[i][2]=z; acc2[i][3]=z; }
  gemm64(hidS, HST, W2p, 4, bkS, acc2, t);
  epilogue_store(acc2, b2S, mS, t);              // m_pre
  __syncthreads();

  // gate = sigmoid(m_pre . Wg + bg) * mask
  {
    int eg = t >> 2, g = t & 3;
    float p = 0.f;
    #pragma unroll
    for (int bq=0;bq<4;++bq){
      short8v s = *reinterpret_cast<const short8v*>(&mS[eg*HST + g*32 + bq*8]);
      #pragma unroll
      for (int j=0;j<8;++j) p += bf2f(s[j]) * wgS[g*32 + bq*8 + j];
    }
    p += __shfl_xor(p, 1); p += __shfl_xor(p, 2);
    if (g == 0) scaleS[eg] = sigf(p + bg[0]) * maskS[eg];
  }
  __syncthreads();

  // m = m_pre * gate * mask; segmented aggregate into magg (cols sorted)
  {
    int o = t & 127, half = t >> 7;
    int ib = half*32;
    float accv = 0.f;
    int curc = colS[ib];
    #pragma unroll 4
    for (int j=0;j<32;++j){
      int i = ib + j;
      int cc = colS[i];
      if (cc != curc){
        atomicAdd(&magg[(size_t)curc*HID + o], accv);
        accv = 0.f; curc = cc;
      }
      int idx = i*HST + o;
      float v = bf2f(mS[idx]) * scaleS[i];
      mS[idx] = bfr(v);
      accv += v;
    }
    atomicAdd(&magg[(size_t)curc*HID + o], accv);
  }
  __syncthreads();

  f32x4 acc3[2][4];
  #pragma unroll
  for (int i=0;i<2;++i){ acc3[i][0]=z; acc3[i][1]=z; acc3[i][2]=z; acc3[i][3]=z; }
  gemm64(mS, HST, C1p, 4, bkS, acc3, t);
  epilogue_store(acc3, bc1S, hidS, t);           // hidden2
  __syncthreads();

  // cw = hidden2 . Wc2 + cb2
  {
    int eg = t >> 2, g = t & 3;
    float p = 0.f;
    #pragma unroll
    for (int bq=0;bq<4;++bq){
      short8v s = *reinterpret_cast<const short8v*>(&hidS[eg*HST + g*32 + bq*8]);
      #pragma unroll
      for (int j=0;j<8;++j) p += bf2f(s[j]) * wc2S[g*32 + bq*8 + j];
    }
    p += __shfl_xor(p, 1); p += __shfl_xor(p, 2);
    if (g == 0) cwS[eg] = p + cb2[0];
  }
  __syncthreads();

  // x_out[col] += coord_diff * cw (segmented)
  if (t < 6){
    int d = t % 3, half = t / 3;
    int ib = half*32;
    float accx = 0.f;
    int curc = colS[ib];
    for (int j=0;j<32;++j){
      int i = ib + j;
      int cc = colS[i];
      if (cc != curc){
        atomicAdd(&xout[curc*3+d], accx);
        accx = 0.f; curc = cc;
      }
      accx += cdS[i][d] * cwS[i];
    }
    atomicAdd(&xout[curc*3+d], accx);
  }
}

// ---------------- node MLP via MFMA: h += silu(h@Wn1a + magg@Wn1b + bn1)@Wn2 + bn2 ----
__global__ __launch_bounds__(256) void node2_kernel(
    float* __restrict__ h, const float* __restrict__ magg,
    const short* __restrict__ W1ap, const short* __restrict__ W1bp,
    const float* __restrict__ bn1,
    const short* __restrict__ Wn2p, const float* __restrict__ bn2)
{
  __shared__ __align__(16) short hT[ME*HST];
  __shared__ __align__(16) short mT[ME*HST];
  __shared__ __align__(16) short bkS[2*5120];
  __shared__ float bn1S[HID], bn2S[HID];
  const int t = threadIdx.x;
  const int n0 = blockIdx.x * ME;
  if (t < HID){ bn1S[t] = bn1[t]; bn2S[t] = bn2[t]; }
  {
    int nl = t >> 2, seg = t & 3;
    int n = n0 + nl; if (n >= NN) n = NN-1;
    const float4* hp = reinterpret_cast<const float4*>(h + (size_t)n*HID + seg*32);
    const float4* mp = reinterpret_cast<const float4*>(magg + (size_t)n*HID + seg*32);
    #pragma unroll
    for (int bq=0;bq<4;++bq){
      float4 u = hp[bq*2], v = hp[bq*2+1];
      short8v s;
      s[0]=bfr(u.x); s[1]=bfr(u.y); s[2]=bfr(u.z); s[3]=bfr(u.w);
      s[4]=bfr(v.x); s[5]=bfr(v.y); s[6]=bfr(v.z); s[7]=bfr(v.w);
      *reinterpret_cast<short8v*>(&hT[nl*HST + seg*32 + bq*8]) = s;
      float4 u2 = mp[bq*2], v2 = mp[bq*2+1];
      short8v s2;
      s2[0]=bfr(u2.x); s2[1]=bfr(u2.y); s2[2]=bfr(u2.z); s2[3]=bfr(u2.w);
      s2[4]=bfr(v2.x); s2[5]=bfr(v2.y); s2[6]=bfr(v2.z); s2[7]=bfr(v2.w);
      *reinterpret_cast<short8v*>(&mT[nl*HST + seg*32 + bq*8]) = s2;
    }
  }
  f32x4 z = {0.f,0.f,0.f,0.f};
  f32x4 acc[2][4];
  #pragma unroll
  for (int i=0;i<2;++i){ acc[i][0]=z; acc[i][1]=z; acc[i][2]=z; acc[i][3]=z; }
  gemm64(hT, HST, W1ap, 4, bkS, acc, t);
  gemm64(mT, HST, W1bp, 4, bkS, acc, t);        // accumulates
  epilogue_store(acc, bn1S, hT, t);              // silu(.+bn1) -> hT
  __syncthreads();

  f32x4 acc2[2][4];
  #pragma unroll
  for (int i=0;i<2;++i){ acc2[i][0]=z; acc2[i][1]=z; acc2[i][2]=z; acc2[i][3]=z; }
  gemm64(hT, HST, Wn2p, 4, bkS, acc2, t);
  const int lane = t & 63, w = t >> 6;
  const int q = lane >> 4, fr = lane & 15;
  #pragma unroll
  for (int et=0; et<2; ++et){
    #pragma unroll
    for (int ot=0; ot<4; ++ot){
      int o = (w>>1)*64 + ot*16 + fr;
      float bv = bn2S[o];
      #pragma unroll
      for (int r=0;r<4;++r){
        int e = (w&1)*32 + et*16 + q*4 + r;
        int n = n0 + e;
        if (n < NN){
          size_t idx = (size_t)n*HID + o;
          h[idx] += acc2[et][ot][r] + bv;
        }
      }
    }
  }
}

__global__ void pool_kernel(const float* __restrict__ h, const int* __restrict__ batch,
                            float* __restrict__ sums, float* __restrict__ counts){
  int o  = threadIdx.x;
  int n0 = blockIdx.x * 16;
  int curg = batch[n0];
  float accv = 0.f, cnt = 0.f;
  for (int j=0;j<16;++j){
    int n = n0 + j;
    int g = batch[n];
    if (g != curg){
      atomicAdd(&sums[(size_t)curg*HID+o], accv);
      if (o==0) atomicAdd(&counts[curg], cnt);
      accv = 0.f; cnt = 0.f; curg = g;
    }
    accv += h[(size_t)n*HID+o];
    cnt  += 1.f;
  }
  atomicAdd(&sums[(size_t)curg*HID+o], accv);
  if (o==0) atomicAdd(&counts[curg], cnt);
}

__global__ void out_kernel(const float* __restrict__ sums, const float* __restrict__ counts,
                           const float* __restrict__ rW, const float* __restrict__ rb,
                           float* __restrict__ out){
  int g = blockIdx.x; int t = threadIdx.x;
  float v = sums[(size_t)g*HID + t]*rW[t] + sums[(size_t)g*HID + 64 + t]*rW[64+t];
  #pragma unroll
  for (int off=32; off>0; off>>=1) v += __shfl_down(v, off);
  if (t==0) out[g] = v / fmaxf(counts[g], 1.0f) + rb[0];
}

extern "C" void kernel_launch(void* const* d_in, const int* in_sizes, int n_in,
                              void* d_out, int out_size, void* d_ws, size_t ws_size,
                              hipStream_t stream)
{
  const float* x_feat = (const float*)d_in[0];
  const float* pos    = (const float*)d_in[1];
  const float* eattr  = (const float*)d_in[2];
  const float* p      = (const float*)d_in[3];
  const float* embW   = (const float*)d_in[4];
  const float* embB   = (const float*)d_in[5];
  const float* eW1    = (const float*)d_in[6];
  const float* eb1    = (const float*)d_in[7];
  const float* eW2    = (const float*)d_in[8];
  const float* eb2    = (const float*)d_in[9];
  const float* gW     = (const float*)d_in[10];
  const float* gb     = (const float*)d_in[11];
  const float* nW1    = (const float*)d_in[12];
  const float* nb1    = (const float*)d_in[13];
  const float* nW2    = (const float*)d_in[14];
  const float* nb2    = (const float*)d_in[15];
  const float* cW1    = (const float*)d_in[16];
  const float* cb1    = (const float*)d_in[17];
  const float* cW2    = (const float*)d_in[18];
  const float* cb2    = (const float*)d_in[19];
  const float* rW     = (const float*)d_in[20];
  const float* rb     = (const float*)d_in[21];
  const int* eidx     = (const int*)d_in[22];
  const int* einv     = (const int*)d_in[23];
  const int* batch    = (const int*)d_in[24];

  float* ws = (float*)d_ws;
  float* h      = ws;  ws += (size_t)NN*HID;
  float* magg   = ws;  ws += (size_t)NN*HID;
  float* xA     = ws;  ws += NN*3;
  float* xB     = ws;  ws += NN*3;
  float* mask   = ws;  ws += NE;
  float* sums   = ws;  ws += (size_t)NG*HID;
  float* counts = ws;  ws += NG;
  int*   hist   = (int*)ws;  ws += NN;
  int*   se     = (int*)ws;  ws += NE;
  short* Abuf = (short*)ws;  ws += (size_t)NN*HID/2;
  short* Bbuf = (short*)ws;  ws += (size_t)NN*HID/2;
  const size_t PK = (size_t)NL*4*HID*32;   // shorts per packed array
  short* W1cp  = (short*)ws;
  short* W1rp  = W1cp  + PK;
  short* W2p   = W1rp  + PK;
  short* C1p   = W2p   + PK;
  short* Wn1ap = C1p   + PK;
  short* Wn1bp = Wn1ap + PK;
  short* Wn2p  = Wn1bp + PK;

  // counting sort of edges by col
  zero_hist<<<(NN+255)/256, 256, 0, stream>>>(hist);
  hist_kernel<<<(NE+255)/256, 256, 0, stream>>>(eidx, hist);
  scan_kernel<<<1, 1024, 0, stream>>>(hist, hist);
  scatter_kernel<<<(NE+255)/256, 256, 0, stream>>>(eidx, hist, se);

  // prepack bf16 weights (each [4][4][128][32])
  const int PG = (int)((PK + 255)/256);
  prepack_kernel<<<PG, 256, 0, stream>>>(eW1, W1cp, 261, 0);
  prepack_kernel<<<PG, 256, 0, stream>>>(eW1, W1rp, 261, 128);
  prepack_kernel<<<PG, 256, 0, stream>>>(eW2, W2p, 128, 0);
  prepack_kernel<<<PG, 256, 0, stream>>>(cW1, C1p, 128, 0);
  prepack_kernel<<<PG, 256, 0, stream>>>(nW1, Wn1ap, 256, 0);
  prepack_kernel<<<PG, 256, 0, stream>>>(nW1, Wn1bp, 256, 128);
  prepack_kernel<<<PG, 256, 0, stream>>>(nW2, Wn2p, 128, 0);

  hipMemcpyAsync(xA, pos, sizeof(float)*NN*3, hipMemcpyDeviceToDevice, stream);
  mask_kernel<<<(NE+255)/256, 256, 0, stream>>>(p, einv, mask);
  embed_kernel<<<NN, HID, 0, stream>>>(x_feat, embW, embB, h);

  float* xc = xA; float* xn = xB;
  for (int l=0;l<NL;++l){
    const size_t wofs = (size_t)l*4*4096;
    nodeproj_kernel<<<NPB, 256, 0, stream>>>(h, W1cp + wofs, eb1 + l*HID,
                                             W1rp + wofs, Abuf, Bbuf);
    hipMemsetAsync(magg, 0, sizeof(float)*(size_t)NN*HID, stream);
    hipMemcpyAsync(xn, xc, sizeof(float)*NN*3, hipMemcpyDeviceToDevice, stream);
    edge2_kernel<<<NE/ME, 256, 0, stream>>>(Abuf, Bbuf, xc, eattr, mask, eidx, se,
        eW1 + (size_t)l*261*HID,
        W2p + wofs, eb2 + l*HID,
        gW  + l*HID, gb + l,
        C1p + wofs, cb1 + l*HID,
        cW2 + l*HID, cb2 + l,
        magg, xn);
    node2_kernel<<<NPB, 256, 0, stream>>>(h, magg,
        Wn1ap + wofs, Wn1bp + wofs, nb1 + l*HID,
        Wn2p + wofs, nb2 + l*HID);
    float* tmp = xc; xc = xn; xn = tmp;
  }
  hipMemsetAsync(sums, 0, sizeof(float)*((size_t)NG*HID + NG), stream);
  pool_kernel<<<NN/16, HID, 0, stream>>>(h, batch, sums, counts);
  out_kernel<<<NG, 64, 0, stream>>>(sums, counts, rW, rb, (float*)d_out);
}

// Round 5
// 1700.796 us; speedup vs baseline: 4.9807x; 1.2476x over previous
//
#include <hip/hip_runtime.h>

#define NN 50000
#define NE 800000
#define HID 128
#define NG 2500
#define NL 4
#define ME 64       // edges (or nodes) per block
#define HST 136     // LDS tile row stride (shorts): 272B -> 2-way max on b128
#define NPB 782     // node blocks: ceil(50000/64)
#define NWG (NE/ME) // 12500 edge blocks

typedef __attribute__((ext_vector_type(8))) short short8v;
typedef __attribute__((ext_vector_type(4))) float f32x4;

__device__ __forceinline__ float sigf(float x){ return 1.0f/(1.0f+__expf(-x)); }
__device__ __forceinline__ float siluf(float x){ return x/(1.0f+__expf(-x)); }
__device__ __forceinline__ short bfr(float x){
  unsigned u = __float_as_uint(x);
  u += 0x7fffu + ((u>>16)&1u);
  return (short)(u>>16);
}
__device__ __forceinline__ float bf2f(short s){
  return __uint_as_float(((unsigned)(unsigned short)s)<<16);
}

// ---------------- counting sort of edges by col ----------------
__global__ void zero_hist(int* __restrict__ hist){
  int i = blockIdx.x*256 + threadIdx.x;
  if (i < NN) hist[i] = 0;
}
__global__ void hist_kernel(const int* __restrict__ eidx, int* __restrict__ hist){
  int e = blockIdx.x*256 + threadIdx.x;
  if (e < NE) atomicAdd(&hist[eidx[NE+e]], 1);
}
__global__ __launch_bounds__(1024) void scan_kernel(const int* __restrict__ hist,
                                                    int* __restrict__ cursor){
  __shared__ int part[1024];
  int t = threadIdx.x;
  const int CH = (NN + 1023)/1024;
  int base = t*CH;
  int s = 0;
  for (int j=0;j<CH;++j){ int i=base+j; if (i<NN) s += hist[i]; }
  part[t] = s; __syncthreads();
  for (int d=1; d<1024; d<<=1){
    int v = (t>=d) ? part[t-d] : 0;
    __syncthreads();
    part[t] += v;
    __syncthreads();
  }
  int ex = (t==0) ? 0 : part[t-1];
  for (int j=0;j<CH;++j){
    int i=base+j;
    if (i<NN){ cursor[i] = ex; ex += hist[i]; }
  }
}
__global__ void scatter_kernel(const int* __restrict__ eidx, int* __restrict__ cursor,
                               int* __restrict__ se){
  int e = blockIdx.x*256 + threadIdx.x;
  if (e < NE){
    int c = eidx[NE+e];
    int pos = atomicAdd(&cursor[c], 1);
    se[pos] = e;
  }
}
// one-time: materialize sorted-order edge streams (rc, ea, mask) — random gathers paid once
__global__ void reorder_kernel(const int* __restrict__ eidx, const int* __restrict__ se,
                               const float* __restrict__ ea, const float* __restrict__ p,
                               const int* __restrict__ inv,
                               int2* __restrict__ rcS, float4* __restrict__ eaS,
                               float* __restrict__ emS){
  int i = blockIdx.x*256 + threadIdx.x;
  if (i < NE){
    int e = se[i];
    int2 rc; rc.x = eidx[e]; rc.y = eidx[NE+e];
    rcS[i] = rc;
    eaS[i] = *reinterpret_cast<const float4*>(ea + (size_t)e*4);
    emS[i] = (p[inv[e]] >= 0.0f) ? 1.0f : 0.0f;
  }
}

// ---- weight prepack: rows [roff,roff+128) of [L][Ktot][128] -> [L][ks4][q4][o128][kk8] bf16
__global__ void prepack_kernel(const float* __restrict__ W, short* __restrict__ out,
                               int Ktot, int roff){
  int idx = blockIdx.x*256 + threadIdx.x;
  if (idx >= NL*4*4*HID*8) return;
  int kk8 = idx & 7;
  int o   = (idx>>3) & 127;
  int q   = (idx>>10) & 3;
  int ks  = (idx>>12) & 3;
  int l   = idx >> 14;
  int k = roff + ks*32 + q*8 + kk8;
  float v = (k < Ktot) ? W[((size_t)l*Ktot + k)*HID + o] : 0.0f;
  out[idx] = bfr(v);
}

__global__ void embed_kernel(const float* __restrict__ xf, const float* __restrict__ W,
                             const float* __restrict__ b, float* __restrict__ h){
  int n = blockIdx.x; int o = threadIdx.x;
  float s = b[o];
  #pragma unroll
  for (int i=0;i<11;++i) s = fmaf(xf[n*11+i], W[i*HID+o], s);
  h[(size_t)n*HID+o] = s;
}

// ---------------- MFMA tile-GEMM: [64 x 128] (LDS bf16) @ [128 x 128] (prepacked) ----
// weight slice layout [q][o][kk8]: linear int4 writes, contiguous conflict-free b128 reads
__device__ __forceinline__ void gemm64(const short* As, int astride,
                                       const short* Wp, int nks,
                                       short* bkS, f32x4 acc[2][4], int t)
{
  const int lane = t & 63, w = t >> 6;
  const int q = lane >> 4, fr = lane & 15;
  const int erow = (w & 1) * 32;
  const int ocol = (w >> 1) * 64;
  const int4* g = reinterpret_cast<const int4*>(Wp);
  int4* bkw = reinterpret_cast<int4*>(bkS);
  int4 p0 = g[t], p1 = g[256 + t];
  for (int ks = 0; ks < nks; ++ks){
    const int buf = (ks & 1) * 512;            // int4 units (4096 shorts)
    bkw[buf + t] = p0; bkw[buf + 256 + t] = p1;
    __syncthreads();
    if (ks + 1 < nks){ p0 = g[(ks+1)*512 + t]; p1 = g[(ks+1)*512 + 256 + t]; }
    const short* bb = bkS + buf*8 + q*1024;
    short8v a[2], b[4];
    #pragma unroll
    for (int et=0; et<2; ++et)
      a[et] = *reinterpret_cast<const short8v*>(As + (erow + et*16 + fr)*astride + ks*32 + q*8);
    #pragma unroll
    for (int ot=0; ot<4; ++ot)
      b[ot] = *reinterpret_cast<const short8v*>(bb + (ocol + ot*16 + fr)*8);
    #pragma unroll
    for (int et=0; et<2; ++et)
      #pragma unroll
      for (int ot=0; ot<4; ++ot)
        acc[et][ot] = __builtin_amdgcn_mfma_f32_16x16x32_bf16(a[et], b[ot], acc[et][ot], 0, 0, 0);
  }
  __syncthreads();
}

// acc -> silu(acc + bias[global]) -> bf16 LDS tile [64][HST]
__device__ __forceinline__ void epilogue_store(const f32x4 acc[2][4],
                                               const float* __restrict__ bias,
                                               short* dst, int t)
{
  const int lane = t & 63, w = t >> 6;
  const int q = lane >> 4, fr = lane & 15;
  #pragma unroll
  for (int et=0; et<2; ++et){
    #pragma unroll
    for (int ot=0; ot<4; ++ot){
      int o = (w>>1)*64 + ot*16 + fr;
      float bv = bias[o];
      #pragma unroll
      for (int r=0;r<4;++r){
        int e = (w&1)*32 + et*16 + q*4 + r;
        dst[e*HST + o] = bfr(siluf(acc[et][ot][r] + bv));
      }
    }
  }
}

// ---------------- per-layer node projections: A = bf16(h@W1hc + b1), B = bf16(h@W1hr) ----
__global__ __launch_bounds__(256) void nodeproj_kernel(
    const float* __restrict__ h,
    const short* __restrict__ Wcp, const float* __restrict__ b1,
    const short* __restrict__ Wrp,
    short* __restrict__ A, short* __restrict__ B)
{
  __shared__ __align__(16) short hT[ME*HST];
  __shared__ __align__(16) short bkS[2*4096];
  const int t = threadIdx.x;
  const int n0 = blockIdx.x * ME;
  {
    int nl = t >> 2, seg = t & 3;
    int n = n0 + nl; if (n >= NN) n = NN-1;
    const float4* hp = reinterpret_cast<const float4*>(h + (size_t)n*HID + seg*32);
    #pragma unroll
    for (int bq=0;bq<4;++bq){
      float4 u = hp[bq*2], v = hp[bq*2+1];
      short8v s;
      s[0]=bfr(u.x); s[1]=bfr(u.y); s[2]=bfr(u.z); s[3]=bfr(u.w);
      s[4]=bfr(v.x); s[5]=bfr(v.y); s[6]=bfr(v.z); s[7]=bfr(v.w);
      *reinterpret_cast<short8v*>(&hT[nl*HST + seg*32 + bq*8]) = s;
    }
  }
  f32x4 z = {0.f,0.f,0.f,0.f};
  f32x4 accA[2][4], accB[2][4];
  #pragma unroll
  for (int i=0;i<2;++i){ accA[i][0]=z;accA[i][1]=z;accA[i][2]=z;accA[i][3]=z;
                         accB[i][0]=z;accB[i][1]=z;accB[i][2]=z;accB[i][3]=z; }
  gemm64(hT, HST, Wcp, 4, bkS, accA, t);
  gemm64(hT, HST, Wrp, 4, bkS, accB, t);
  const int lane = t & 63, w = t >> 6;
  const int q = lane >> 4, fr = lane & 15;
  #pragma unroll
  for (int et=0; et<2; ++et){
    #pragma unroll
    for (int ot=0; ot<4; ++ot){
      int o = (w>>1)*64 + ot*16 + fr;
      float bv = b1[o];
      #pragma unroll
      for (int r=0;r<4;++r){
        int e = (w&1)*32 + et*16 + q*4 + r;
        int n = n0 + e;
        if (n < NN){
          A[(size_t)n*HID + o] = bfr(accA[et][ot][r] + bv);
          B[(size_t)n*HID + o] = bfr(accB[et][ot][r]);
        }
      }
    }
  }
}

// ---------------- edge kernel ----------------
__global__ __launch_bounds__(256) void edge2_kernel(
    const short* __restrict__ A, const short* __restrict__ B,
    const float* __restrict__ x,
    const int2* __restrict__ rcS, const float4* __restrict__ eaS,
    const float* __restrict__ emS,
    const float* __restrict__ wrow,   // eW1 + l*261*128 : rows 256..260 = wd, wea
    const short* __restrict__ W2p, const float* __restrict__ b2,
    const float* __restrict__ Wg, const float* __restrict__ bg,
    const short* __restrict__ C1p, const float* __restrict__ bc1,
    const float* __restrict__ Wc2, const float* __restrict__ cb2,
    float* __restrict__ magg, float* __restrict__ xout)
{
  __shared__ __align__(16) short hidS[ME*HST];   // hidden1 -> m_pre -> m -> hidden2 (in-place)
  __shared__ __align__(16) short bkS[2*4096];
  __shared__ float wdS[HID];
  __shared__ float weaS[4][HID];
  __shared__ float maskS[ME], scaleS[ME], cwS[ME], distS[ME], cdS[ME][3];
  __shared__ int colS[ME];

  const int t = threadIdx.x;
  // bijective XCD swizzle (m204): adjacent data chunks land on one XCD's L2
  const int xcd = blockIdx.x & 7, sub = blockIdx.x >> 3;
  const int qq = NWG >> 3, rr = NWG & 7;
  const int bid = (xcd < rr ? xcd*(qq+1) : rr*(qq+1) + (xcd-rr)*qq) + sub;
  const int i0 = bid * ME;

  // issue per-thread gathers early (4 threads/edge, 32 channels each)
  const int el = t >> 2, seg = t & 3;
  const int2 rc = rcS[i0 + el];
  const int4* Ap = reinterpret_cast<const int4*>(A + (size_t)rc.y*HID + seg*32);
  const int4* Bp = reinterpret_cast<const int4*>(B + (size_t)rc.x*HID + seg*32);
  int4 av0=Ap[0], av1=Ap[1], av2=Ap[2], av3=Ap[3];
  int4 bv0=Bp[0], bv1=Bp[1], bv2=Bp[2], bv3=Bp[3];
  float4 eav = eaS[i0 + el];

  if (t < HID){
    wdS[t] = wrow[256*HID + t];
    #pragma unroll
    for (int j=0;j<4;++j) weaS[j][t] = wrow[(257+j)*HID + t];
  }
  if (t < ME){
    int2 rc2 = rcS[i0 + t];
    colS[t] = rc2.y; maskS[t] = emS[i0 + t];
    float dx = x[rc2.y*3+0]-x[rc2.x*3+0];
    float dy = x[rc2.y*3+1]-x[rc2.x*3+1];
    float dz = x[rc2.y*3+2]-x[rc2.x*3+2];
    cdS[t][0]=dx; cdS[t][1]=dy; cdS[t][2]=dz;
    distS[t] = sqrtf(dx*dx+dy*dy+dz*dz);
  }
  __syncthreads();

  // hidden1 = silu(A[col] + B[row] + dist*wd + ea@wea)
  {
    float de = distS[el];
    const int4 avs[4] = {av0,av1,av2,av3};
    const int4 bvs[4] = {bv0,bv1,bv2,bv3};
    #pragma unroll
    for (int bq=0;bq<4;++bq){
      short8v a8 = *reinterpret_cast<const short8v*>(&avs[bq]);
      short8v b8 = *reinterpret_cast<const short8v*>(&bvs[bq]);
      short8v s;
      #pragma unroll
      for (int j=0;j<8;++j){
        int o = seg*32 + bq*8 + j;
        float v = bf2f(a8[j]) + bf2f(b8[j]) + de*wdS[o]
                + eav.x*weaS[0][o] + eav.y*weaS[1][o]
                + eav.z*weaS[2][o] + eav.w*weaS[3][o];
        s[j] = bfr(siluf(v));
      }
      *reinterpret_cast<short8v*>(&hidS[el*HST + seg*32 + bq*8]) = s;
    }
  }
  // gemm64's first loop-top barrier publishes hidS

  f32x4 z = {0.f,0.f,0.f,0.f};
  f32x4 acc2[2][4];
  #pragma unroll
  for (int i=0;i<2;++i){ acc2[i][0]=z; acc2[i][1]=z; acc2[i][2]=z; acc2[i][3]=z; }
  gemm64(hidS, HST, W2p, 4, bkS, acc2, t);
  epilogue_store(acc2, b2, hidS, t);              // m_pre (in-place)
  __syncthreads();

  // gate = sigmoid(m_pre . Wg + bg) * mask
  {
    int eg = t >> 2, g = t & 3;
    float p = 0.f;
    #pragma unroll
    for (int bq=0;bq<4;++bq){
      short8v s = *reinterpret_cast<const short8v*>(&hidS[eg*HST + g*32 + bq*8]);
      #pragma unroll
      for (int j=0;j<8;++j) p += bf2f(s[j]) * Wg[g*32 + bq*8 + j];
    }
    p += __shfl_xor(p, 1); p += __shfl_xor(p, 2);
    if (g == 0) scaleS[eg] = sigf(p + bg[0]) * maskS[eg];
  }
  __syncthreads();

  // m = m_pre * gate * mask; segmented aggregate into magg (cols sorted)
  {
    int o = t & 127, half = t >> 7;
    int ib = half*32;
    float accv = 0.f;
    int curc = colS[ib];
    #pragma unroll 4
    for (int j=0;j<32;++j){
      int i = ib + j;
      int cc = colS[i];
      if (cc != curc){
        atomicAdd(&magg[(size_t)curc*HID + o], accv);
        accv = 0.f; curc = cc;
      }
      int idx = i*HST + o;
      float v = bf2f(hidS[idx]) * scaleS[i];
      hidS[idx] = bfr(v);
      accv += v;
    }
    atomicAdd(&magg[(size_t)curc*HID + o], accv);
  }
  __syncthreads();

  f32x4 acc3[2][4];
  #pragma unroll
  for (int i=0;i<2;++i){ acc3[i][0]=z; acc3[i][1]=z; acc3[i][2]=z; acc3[i][3]=z; }
  gemm64(hidS, HST, C1p, 4, bkS, acc3, t);
  epilogue_store(acc3, bc1, hidS, t);             // hidden2 (in-place)
  __syncthreads();

  // cw = hidden2 . Wc2 + cb2
  {
    int eg = t >> 2, g = t & 3;
    float p = 0.f;
    #pragma unroll
    for (int bq=0;bq<4;++bq){
      short8v s = *reinterpret_cast<const short8v*>(&hidS[eg*HST + g*32 + bq*8]);
      #pragma unroll
      for (int j=0;j<8;++j) p += bf2f(s[j]) * Wc2[g*32 + bq*8 + j];
    }
    p += __shfl_xor(p, 1); p += __shfl_xor(p, 2);
    if (g == 0) cwS[eg] = p + cb2[0];
  }
  __syncthreads();

  // x_out[col] += coord_diff * cw (segmented)
  if (t < 6){
    int d = t % 3, half = t / 3;
    int ib = half*32;
    float accx = 0.f;
    int curc = colS[ib];
    for (int j=0;j<32;++j){
      int i = ib + j;
      int cc = colS[i];
      if (cc != curc){
        atomicAdd(&xout[curc*3+d], accx);
        accx = 0.f; curc = cc;
      }
      accx += cdS[i][d] * cwS[i];
    }
    atomicAdd(&xout[curc*3+d], accx);
  }
}

// ---------------- node MLP via MFMA: h += silu(h@Wn1a + magg@Wn1b + bn1)@Wn2 + bn2 ----
__global__ __launch_bounds__(256) void node2_kernel(
    float* __restrict__ h, const float* __restrict__ magg,
    const short* __restrict__ W1ap, const short* __restrict__ W1bp,
    const float* __restrict__ bn1,
    const short* __restrict__ Wn2p, const float* __restrict__ bn2)
{
  __shared__ __align__(16) short hT[ME*HST];
  __shared__ __align__(16) short mT[ME*HST];
  __shared__ __align__(16) short bkS[2*4096];
  const int t = threadIdx.x;
  const int n0 = blockIdx.x * ME;
  {
    int nl = t >> 2, seg = t & 3;
    int n = n0 + nl; if (n >= NN) n = NN-1;
    const float4* hp = reinterpret_cast<const float4*>(h + (size_t)n*HID + seg*32);
    const float4* mp = reinterpret_cast<const float4*>(magg + (size_t)n*HID + seg*32);
    #pragma unroll
    for (int bq=0;bq<4;++bq){
      float4 u = hp[bq*2], v = hp[bq*2+1];
      short8v s;
      s[0]=bfr(u.x); s[1]=bfr(u.y); s[2]=bfr(u.z); s[3]=bfr(u.w);
      s[4]=bfr(v.x); s[5]=bfr(v.y); s[6]=bfr(v.z); s[7]=bfr(v.w);
      *reinterpret_cast<short8v*>(&hT[nl*HST + seg*32 + bq*8]) = s;
      float4 u2 = mp[bq*2], v2 = mp[bq*2+1];
      short8v s2;
      s2[0]=bfr(u2.x); s2[1]=bfr(u2.y); s2[2]=bfr(u2.z); s2[3]=bfr(u2.w);
      s2[4]=bfr(v2.x); s2[5]=bfr(v2.y); s2[6]=bfr(v2.z); s2[7]=bfr(v2.w);
      *reinterpret_cast<short8v*>(&mT[nl*HST + seg*32 + bq*8]) = s2;
    }
  }
  f32x4 z = {0.f,0.f,0.f,0.f};
  f32x4 acc[2][4];
  #pragma unroll
  for (int i=0;i<2;++i){ acc[i][0]=z; acc[i][1]=z; acc[i][2]=z; acc[i][3]=z; }
  gemm64(hT, HST, W1ap, 4, bkS, acc, t);
  gemm64(mT, HST, W1bp, 4, bkS, acc, t);        // accumulates
  epilogue_store(acc, bn1, hT, t);               // silu(.+bn1) -> hT (in-place)
  __syncthreads();

  f32x4 acc2[2][4];
  #pragma unroll
  for (int i=0;i<2;++i){ acc2[i][0]=z; acc2[i][1]=z; acc2[i][2]=z; acc2[i][3]=z; }
  gemm64(hT, HST, Wn2p, 4, bkS, acc2, t);
  const int lane = t & 63, w = t >> 6;
  const int q = lane >> 4, fr = lane & 15;
  #pragma unroll
  for (int et=0; et<2; ++et){
    #pragma unroll
    for (int ot=0; ot<4; ++ot){
      int o = (w>>1)*64 + ot*16 + fr;
      float bv = bn2[o];
      #pragma unroll
      for (int r=0;r<4;++r){
        int e = (w&1)*32 + et*16 + q*4 + r;
        int n = n0 + e;
        if (n < NN){
          size_t idx = (size_t)n*HID + o;
          h[idx] += acc2[et][ot][r] + bv;
        }
      }
    }
  }
}

__global__ void pool_kernel(const float* __restrict__ h, const int* __restrict__ batch,
                            float* __restrict__ sums, float* __restrict__ counts){
  int o  = threadIdx.x;
  int n0 = blockIdx.x * 16;
  int curg = batch[n0];
  float accv = 0.f, cnt = 0.f;
  for (int j=0;j<16;++j){
    int n = n0 + j;
    int g = batch[n];
    if (g != curg){
      atomicAdd(&sums[(size_t)curg*HID+o], accv);
      if (o==0) atomicAdd(&counts[curg], cnt);
      accv = 0.f; cnt = 0.f; curg = g;
    }
    accv += h[(size_t)n*HID+o];
    cnt  += 1.f;
  }
  atomicAdd(&sums[(size_t)curg*HID+o], accv);
  if (o==0) atomicAdd(&counts[curg], cnt);
}

__global__ void out_kernel(const float* __restrict__ sums, const float* __restrict__ counts,
                           const float* __restrict__ rW, const float* __restrict__ rb,
                           float* __restrict__ out){
  int g = blockIdx.x; int t = threadIdx.x;
  float v = sums[(size_t)g*HID + t]*rW[t] + sums[(size_t)g*HID + 64 + t]*rW[64+t];
  #pragma unroll
  for (int off=32; off>0; off>>=1) v += __shfl_down(v, off);
  if (t==0) out[g] = v / fmaxf(counts[g], 1.0f) + rb[0];
}

extern "C" void kernel_launch(void* const* d_in, const int* in_sizes, int n_in,
                              void* d_out, int out_size, void* d_ws, size_t ws_size,
                              hipStream_t stream)
{
  const float* x_feat = (const float*)d_in[0];
  const float* pos    = (const float*)d_in[1];
  const float* eattr  = (const float*)d_in[2];
  const float* p      = (const float*)d_in[3];
  const float* embW   = (const float*)d_in[4];
  const float* embB   = (const float*)d_in[5];
  const float* eW1    = (const float*)d_in[6];
  const float* eb1    = (const float*)d_in[7];
  const float* eW2    = (const float*)d_in[8];
  const float* eb2    = (const float*)d_in[9];
  const float* gW     = (const float*)d_in[10];
  const float* gb     = (const float*)d_in[11];
  const float* nW1    = (const float*)d_in[12];
  const float* nb1    = (const float*)d_in[13];
  const float* nW2    = (const float*)d_in[14];
  const float* nb2    = (const float*)d_in[15];
  const float* cW1    = (const float*)d_in[16];
  const float* cb1    = (const float*)d_in[17];
  const float* cW2    = (const float*)d_in[18];
  const float* cb2    = (const float*)d_in[19];
  const float* rW     = (const float*)d_in[20];
  const float* rb     = (const float*)d_in[21];
  const int* eidx     = (const int*)d_in[22];
  const int* einv     = (const int*)d_in[23];
  const int* batch    = (const int*)d_in[24];

  float* ws = (float*)d_ws;
  float* h      = ws;  ws += (size_t)NN*HID;
  float* magg   = ws;  ws += (size_t)NN*HID;
  float* xA     = ws;  ws += NN*3;
  float* xB     = ws;  ws += NN*3;
  float* sums   = ws;  ws += (size_t)NG*HID;
  float* counts = ws;  ws += NG;
  int*   hist   = (int*)ws;  ws += NN;
  int*   se     = (int*)ws;  ws += NE;
  int2*  rcS    = (int2*)ws;  ws += (size_t)NE*2;
  float4* eaS   = (float4*)ws; ws += (size_t)NE*4;
  float* emS    = ws;  ws += NE;
  short* Abuf = (short*)ws;  ws += (size_t)NN*HID/2;
  short* Bbuf = (short*)ws;  ws += (size_t)NN*HID/2;
  const size_t PK = (size_t)NL*4*4*HID*8;   // shorts per packed array
  short* W1cp  = (short*)ws;
  short* W1rp  = W1cp  + PK;
  short* W2p   = W1rp  + PK;
  short* C1p   = W2p   + PK;
  short* Wn1ap = C1p   + PK;
  short* Wn1bp = Wn1ap + PK;
  short* Wn2p  = Wn1bp + PK;

  // counting sort of edges by col, then materialize sorted streams
  zero_hist<<<(NN+255)/256, 256, 0, stream>>>(hist);
  hist_kernel<<<(NE+255)/256, 256, 0, stream>>>(eidx, hist);
  scan_kernel<<<1, 1024, 0, stream>>>(hist, hist);
  scatter_kernel<<<(NE+255)/256, 256, 0, stream>>>(eidx, hist, se);
  reorder_kernel<<<(NE+255)/256, 256, 0, stream>>>(eidx, se, eattr, p, einv,
                                                   rcS, eaS, emS);

  // prepack bf16 weights (each [L][4][4][128][8])
  const int PG = (int)((PK + 255)/256);
  prepack_kernel<<<PG, 256, 0, stream>>>(eW1, W1cp, 261, 0);
  prepack_kernel<<<PG, 256, 0, stream>>>(eW1, W1rp, 261, 128);
  prepack_kernel<<<PG, 256, 0, stream>>>(eW2, W2p, 128, 0);
  prepack_kernel<<<PG, 256, 0, stream>>>(cW1, C1p, 128, 0);
  prepack_kernel<<<PG, 256, 0, stream>>>(nW1, Wn1ap, 256, 0);
  prepack_kernel<<<PG, 256, 0, stream>>>(nW1, Wn1bp, 256, 128);
  prepack_kernel<<<PG, 256, 0, stream>>>(nW2, Wn2p, 128, 0);

  hipMemcpyAsync(xA, pos, sizeof(float)*NN*3, hipMemcpyDeviceToDevice, stream);
  embed_kernel<<<NN, HID, 0, stream>>>(x_feat, embW, embB, h);

  float* xc = xA; float* xn = xB;
  for (int l=0;l<NL;++l){
    const size_t wofs = (size_t)l*4*4096;
    nodeproj_kernel<<<NPB, 256, 0, stream>>>(h, W1cp + wofs, eb1 + l*HID,
                                             W1rp + wofs, Abuf, Bbuf);
    hipMemsetAsync(magg, 0, sizeof(float)*(size_t)NN*HID, stream);
    hipMemcpyAsync(xn, xc, sizeof(float)*NN*3, hipMemcpyDeviceToDevice, stream);
    edge2_kernel<<<NWG, 256, 0, stream>>>(Abuf, Bbuf, xc, rcS, eaS, emS,
        eW1 + (size_t)l*261*HID,
        W2p + wofs, eb2 + l*HID,
        gW  + l*HID, gb + l,
        C1p + wofs, cb1 + l*HID,
        cW2 + l*HID, cb2 + l,
        magg, xn);
    node2_kernel<<<NPB, 256, 0, stream>>>(h, magg,
        Wn1ap + wofs, Wn1bp + wofs, nb1 + l*HID,
        Wn2p + wofs, nb2 + l*HID);
    float* tmp = xc; xc = xn; xn = tmp;
  }
  hipMemsetAsync(sums, 0, sizeof(float)*((size_t)NG*HID + NG), stream);
  pool_kernel<<<NN/16, HID, 0, stream>>>(h, batch, sums, counts);
  out_kernel<<<NG, 64, 0, stream>>>(sums, counts, rW, rb, (float*)d_out);
}

// Round 6
// 1612.093 us; speedup vs baseline: 5.2547x; 1.0550x over previous
//
#include <hip/hip_runtime.h>

#define NN 50000
#define NE 800000
#define HID 128
#define NG 2500
#define NL 4
#define ME 64       // edges (or nodes) per block
#define HST 136     // LDS tile row stride (shorts): 272B -> 2-way max on b128
#define NPB 782     // node blocks: ceil(50000/64)
#define NWG (NE/ME) // 12500 edge blocks

typedef __attribute__((ext_vector_type(8))) short short8v;
typedef __attribute__((ext_vector_type(4))) float f32x4;

__device__ __forceinline__ float sigf(float x){ return 1.0f/(1.0f+__expf(-x)); }
__device__ __forceinline__ float siluf(float x){ return x/(1.0f+__expf(-x)); }
__device__ __forceinline__ short bfr(float x){           // scalar fallback (RNE)
  unsigned u = __float_as_uint(x);
  u += 0x7fffu + ((u>>16)&1u);
  return (short)(u>>16);
}
// packed f32x2 -> bf16x2 (RNE), lo -> [15:0], hi -> [31:16]
__device__ __forceinline__ unsigned cvtpk(float lo, float hi){
  unsigned r;
  asm("v_cvt_pk_bf16_f32 %0, %1, %2" : "=v"(r) : "v"(lo), "v"(hi));
  return r;
}
__device__ __forceinline__ float bf2f(short s){
  return __uint_as_float(((unsigned)(unsigned short)s)<<16);
}

// ---------------- counting sort of edges by col ----------------
__global__ void zero_hist(int* __restrict__ hist){
  int i = blockIdx.x*256 + threadIdx.x;
  if (i < NN) hist[i] = 0;
}
__global__ void hist_kernel(const int* __restrict__ eidx, int* __restrict__ hist){
  int e = blockIdx.x*256 + threadIdx.x;
  if (e < NE) atomicAdd(&hist[eidx[NE+e]], 1);
}
__global__ __launch_bounds__(1024) void scan_kernel(const int* __restrict__ hist,
                                                    int* __restrict__ cursor){
  __shared__ int part[1024];
  int t = threadIdx.x;
  const int CH = (NN + 1023)/1024;
  int base = t*CH;
  int s = 0;
  for (int j=0;j<CH;++j){ int i=base+j; if (i<NN) s += hist[i]; }
  part[t] = s; __syncthreads();
  for (int d=1; d<1024; d<<=1){
    int v = (t>=d) ? part[t-d] : 0;
    __syncthreads();
    part[t] += v;
    __syncthreads();
  }
  int ex = (t==0) ? 0 : part[t-1];
  for (int j=0;j<CH;++j){
    int i=base+j;
    if (i<NN){ cursor[i] = ex; ex += hist[i]; }
  }
}
__global__ void scatter_kernel(const int* __restrict__ eidx, int* __restrict__ cursor,
                               int* __restrict__ se){
  int e = blockIdx.x*256 + threadIdx.x;
  if (e < NE){
    int c = eidx[NE+e];
    int pos = atomicAdd(&cursor[c], 1);
    se[pos] = e;
  }
}
// one-time: materialize sorted-order edge streams (random gathers paid once)
__global__ void reorder_kernel(const int* __restrict__ eidx, const int* __restrict__ se,
                               const float* __restrict__ ea, const float* __restrict__ p,
                               const int* __restrict__ inv,
                               int2* __restrict__ rcS, float4* __restrict__ eaS,
                               float* __restrict__ emS){
  int i = blockIdx.x*256 + threadIdx.x;
  if (i < NE){
    int e = se[i];
    int2 rc; rc.x = eidx[e]; rc.y = eidx[NE+e];
    rcS[i] = rc;
    eaS[i] = *reinterpret_cast<const float4*>(ea + (size_t)e*4);
    emS[i] = (p[inv[e]] >= 0.0f) ? 1.0f : 0.0f;
  }
}

// ---- weight prepack: rows [roff,roff+128) of [L][Ktot][128] -> [L][ks4][q4][o128][kk8] bf16
__global__ void prepack_kernel(const float* __restrict__ W, short* __restrict__ out,
                               int Ktot, int roff){
  int idx = blockIdx.x*256 + threadIdx.x;
  if (idx >= NL*4*4*HID*8) return;
  int kk8 = idx & 7;
  int o   = (idx>>3) & 127;
  int q   = (idx>>10) & 3;
  int ks  = (idx>>12) & 3;
  int l   = idx >> 14;
  int k = roff + ks*32 + q*8 + kk8;
  float v = (k < Ktot) ? W[((size_t)l*Ktot + k)*HID + o] : 0.0f;
  out[idx] = bfr(v);
}

__global__ void embed_kernel(const float* __restrict__ xf, const float* __restrict__ W,
                             const float* __restrict__ b, float* __restrict__ h){
  int n = blockIdx.x; int o = threadIdx.x;
  float s = b[o];
  #pragma unroll
  for (int i=0;i<11;++i) s = fmaf(xf[n*11+i], W[i*HID+o], s);
  h[(size_t)n*HID+o] = s;
}

// ---------------- MFMA tile-GEMM: [64 x 128] (LDS bf16) @ [128 x 128] (prepacked) ----
__device__ __forceinline__ void gemm64(const short* As, int astride,
                                       const short* Wp, int nks,
                                       short* bkS, f32x4 acc[2][4], int t)
{
  const int lane = t & 63, w = t >> 6;
  const int q = lane >> 4, fr = lane & 15;
  const int erow = (w & 1) * 32;
  const int ocol = (w >> 1) * 64;
  const int4* g = reinterpret_cast<const int4*>(Wp);
  int4* bkw = reinterpret_cast<int4*>(bkS);
  int4 p0 = g[t], p1 = g[256 + t];
  for (int ks = 0; ks < nks; ++ks){
    const int buf = (ks & 1) * 512;            // int4 units (4096 shorts)
    bkw[buf + t] = p0; bkw[buf + 256 + t] = p1;
    __syncthreads();
    if (ks + 1 < nks){ p0 = g[(ks+1)*512 + t]; p1 = g[(ks+1)*512 + 256 + t]; }
    const short* bb = bkS + buf*8 + q*1024;
    short8v a[2], b[4];
    #pragma unroll
    for (int et=0; et<2; ++et)
      a[et] = *reinterpret_cast<const short8v*>(As + (erow + et*16 + fr)*astride + ks*32 + q*8);
    #pragma unroll
    for (int ot=0; ot<4; ++ot)
      b[ot] = *reinterpret_cast<const short8v*>(bb + (ocol + ot*16 + fr)*8);
    #pragma unroll
    for (int et=0; et<2; ++et)
      #pragma unroll
      for (int ot=0; ot<4; ++ot)
        acc[et][ot] = __builtin_amdgcn_mfma_f32_16x16x32_bf16(a[et], b[ot], acc[et][ot], 0, 0, 0);
  }
  __syncthreads();
}

// acc -> silu(scale*acc + bias) -> bf16 LDS tile [64][HST]; scaleS==nullptr -> scale=1
__device__ __forceinline__ void epilogue_store(const f32x4 acc[2][4],
                                               const float* __restrict__ bias,
                                               const float* __restrict__ scaleS,
                                               short* dst, int t)
{
  const int lane = t & 63, w = t >> 6;
  const int q = lane >> 4, fr = lane & 15;
  #pragma unroll
  for (int et=0; et<2; ++et){
    const int e0 = (w&1)*32 + et*16 + q*4;
    float s0=1.f,s1=1.f,s2=1.f,s3=1.f;
    if (scaleS){ s0=scaleS[e0]; s1=scaleS[e0+1]; s2=scaleS[e0+2]; s3=scaleS[e0+3]; }
    #pragma unroll
    for (int ot=0; ot<4; ++ot){
      int o = (w>>1)*64 + ot*16 + fr;
      float bv = bias[o];
      unsigned p01 = cvtpk(siluf(fmaf(s0,acc[et][ot][0],bv)), siluf(fmaf(s1,acc[et][ot][1],bv)));
      unsigned p23 = cvtpk(siluf(fmaf(s2,acc[et][ot][2],bv)), siluf(fmaf(s3,acc[et][ot][3],bv)));
      dst[(e0+0)*HST + o] = (short)p01;
      dst[(e0+1)*HST + o] = (short)(p01>>16);
      dst[(e0+2)*HST + o] = (short)p23;
      dst[(e0+3)*HST + o] = (short)(p23>>16);
    }
  }
}

// ---------------- layer-0 node projections: A = bf16(h@W1hc + b1), B = bf16(h@W1hr) ----
__global__ __launch_bounds__(256) void nodeproj_kernel(
    const float* __restrict__ h,
    const short* __restrict__ Wcp, const float* __restrict__ b1,
    const short* __restrict__ Wrp,
    short* __restrict__ A, short* __restrict__ B)
{
  __shared__ __align__(16) short hT[ME*HST];
  __shared__ __align__(16) short bkS[2*4096];
  const int t = threadIdx.x;
  const int n0 = blockIdx.x * ME;
  {
    int nl = t >> 2, seg = t & 3;
    int n = n0 + nl; if (n >= NN) n = NN-1;
    const float4* hp = reinterpret_cast<const float4*>(h + (size_t)n*HID + seg*32);
    #pragma unroll
    for (int bq=0;bq<4;++bq){
      float4 u = hp[bq*2], v = hp[bq*2+1];
      int4 sv;
      sv.x = (int)cvtpk(u.x,u.y); sv.y = (int)cvtpk(u.z,u.w);
      sv.z = (int)cvtpk(v.x,v.y); sv.w = (int)cvtpk(v.z,v.w);
      *reinterpret_cast<int4*>(&hT[nl*HST + seg*32 + bq*8]) = sv;
    }
  }
  f32x4 z = {0.f,0.f,0.f,0.f};
  f32x4 accA[2][4], accB[2][4];
  #pragma unroll
  for (int i=0;i<2;++i){ accA[i][0]=z;accA[i][1]=z;accA[i][2]=z;accA[i][3]=z;
                         accB[i][0]=z;accB[i][1]=z;accB[i][2]=z;accB[i][3]=z; }
  gemm64(hT, HST, Wcp, 4, bkS, accA, t);
  gemm64(hT, HST, Wrp, 4, bkS, accB, t);
  const int lane = t & 63, w = t >> 6;
  const int q = lane >> 4, fr = lane & 15;
  #pragma unroll
  for (int et=0; et<2; ++et){
    int e0 = (w&1)*32 + et*16 + q*4;
    #pragma unroll
    for (int ot=0; ot<4; ++ot){
      int o = (w>>1)*64 + ot*16 + fr;
      float bv = b1[o];
      #pragma unroll
      for (int r=0;r<4;++r){
        int n = n0 + e0 + r;
        if (n < NN){
          A[(size_t)n*HID + o] = bfr(accA[et][ot][r] + bv);
          B[(size_t)n*HID + o] = bfr(accB[et][ot][r]);
        }
      }
    }
  }
}

// ---------------- edge kernel ----------------
__global__ __launch_bounds__(256) void edge2_kernel(
    const short* __restrict__ A, const short* __restrict__ B,
    const float* __restrict__ x,
    const int2* __restrict__ rcS, const float4* __restrict__ eaS,
    const float* __restrict__ emS,
    const float* __restrict__ wrow,   // eW1 + l*261*128 : rows 256..260 = wd, wea
    const short* __restrict__ W2p, const float* __restrict__ b2,
    const float* __restrict__ Wg, const float* __restrict__ bg,
    const short* __restrict__ C1p, const float* __restrict__ bc1,
    const float* __restrict__ Wc2, const float* __restrict__ cb2,
    float* __restrict__ magg, float* __restrict__ xout)
{
  __shared__ __align__(16) short hidS[ME*HST];   // hidden1 -> m_pre (kept) -> hidden2
  __shared__ __align__(16) short bkS[2*4096];
  __shared__ float wdS[HID], wgS[HID], wc2S[HID];
  __shared__ float weaS[4][HID];
  __shared__ float maskS[ME], scaleS[ME], cwS[ME], distS[ME], cdS[ME][3];
  __shared__ int colS[ME];

  const int t = threadIdx.x;
  // bijective XCD swizzle (m204)
  const int xcd = blockIdx.x & 7, sub = blockIdx.x >> 3;
  const int qq = NWG >> 3, rr = NWG & 7;
  const int bid = (xcd < rr ? xcd*(qq+1) : rr*(qq+1) + (xcd-rr)*qq) + sub;
  const int i0 = bid * ME;

  // issue per-thread gathers early (4 threads/edge, 32 channels each)
  const int el = t >> 2, seg = t & 3;
  const int2 rc = rcS[i0 + el];
  const int4* Ap = reinterpret_cast<const int4*>(A + (size_t)rc.y*HID + seg*32);
  const int4* Bp = reinterpret_cast<const int4*>(B + (size_t)rc.x*HID + seg*32);
  int4 av0=Ap[0], av1=Ap[1], av2=Ap[2], av3=Ap[3];
  int4 bv0=Bp[0], bv1=Bp[1], bv2=Bp[2], bv3=Bp[3];
  float4 eav = eaS[i0 + el];

  if (t < HID){
    wdS[t] = wrow[256*HID + t];
    wgS[t] = Wg[t]; wc2S[t] = Wc2[t];
    #pragma unroll
    for (int j=0;j<4;++j) weaS[j][t] = wrow[(257+j)*HID + t];
  }
  if (t < ME){
    int2 rc2 = rcS[i0 + t];
    colS[t] = rc2.y; maskS[t] = emS[i0 + t];
    float dx = x[rc2.y*3+0]-x[rc2.x*3+0];
    float dy = x[rc2.y*3+1]-x[rc2.x*3+1];
    float dz = x[rc2.y*3+2]-x[rc2.x*3+2];
    cdS[t][0]=dx; cdS[t][1]=dy; cdS[t][2]=dz;
    distS[t] = sqrtf(dx*dx+dy*dy+dz*dz);
  }
  __syncthreads();

  // hidden1 = silu(A[col] + B[row] + dist*wd + ea@wea)
  {
    float de = distS[el];
    const int4 avs[4] = {av0,av1,av2,av3};
    const int4 bvs[4] = {bv0,bv1,bv2,bv3};
    #pragma unroll
    for (int bq=0;bq<4;++bq){
      short8v a8 = *reinterpret_cast<const short8v*>(&avs[bq]);
      short8v b8 = *reinterpret_cast<const short8v*>(&bvs[bq]);
      float f[8];
      #pragma unroll
      for (int j=0;j<8;++j){
        int o = seg*32 + bq*8 + j;
        float v = bf2f(a8[j]) + bf2f(b8[j]) + de*wdS[o]
                + eav.x*weaS[0][o] + eav.y*weaS[1][o]
                + eav.z*weaS[2][o] + eav.w*weaS[3][o];
        f[j] = siluf(v);
      }
      int4 sv;
      sv.x = (int)cvtpk(f[0],f[1]); sv.y = (int)cvtpk(f[2],f[3]);
      sv.z = (int)cvtpk(f[4],f[5]); sv.w = (int)cvtpk(f[6],f[7]);
      *reinterpret_cast<int4*>(&hidS[el*HST + seg*32 + bq*8]) = sv;
    }
  }
  // gemm64's first loop-top barrier publishes hidS

  f32x4 z = {0.f,0.f,0.f,0.f};
  f32x4 acc2[2][4];
  #pragma unroll
  for (int i=0;i<2;++i){ acc2[i][0]=z; acc2[i][1]=z; acc2[i][2]=z; acc2[i][3]=z; }
  gemm64(hidS, HST, W2p, 4, bkS, acc2, t);
  epilogue_store(acc2, b2, nullptr, hidS, t);     // m_pre (in-place)
  __syncthreads();

  // gate = sigmoid(m_pre . Wg + bg) * mask
  {
    int eg = t >> 2, g = t & 3;
    float p = 0.f;
    #pragma unroll
    for (int bq=0;bq<4;++bq){
      short8v s = *reinterpret_cast<const short8v*>(&hidS[eg*HST + g*32 + bq*8]);
      #pragma unroll
      for (int j=0;j<8;++j) p += bf2f(s[j]) * wgS[g*32 + bq*8 + j];
    }
    p += __shfl_xor(p, 1); p += __shfl_xor(p, 2);
    if (g == 0) scaleS[eg] = sigf(p + bg[0]) * maskS[eg];
  }
  __syncthreads();

  // magg[col] += m_pre * scale (segmented; m_pre NOT modified — scale folded into C1)
  {
    int o = t & 127, half = t >> 7;
    int ib = half*32;
    float accv = 0.f;
    int curc = colS[ib];
    #pragma unroll 4
    for (int j=0;j<32;++j){
      int i = ib + j;
      int cc = colS[i];
      if (cc != curc){
        atomicAdd(&magg[(size_t)curc*HID + o], accv);
        accv = 0.f; curc = cc;
      }
      accv += bf2f(hidS[i*HST + o]) * scaleS[i];
    }
    atomicAdd(&magg[(size_t)curc*HID + o], accv);
  }
  __syncthreads();

  // hidden2 = silu(scale * (m_pre @ Wc1) + bc1)
  f32x4 acc3[2][4];
  #pragma unroll
  for (int i=0;i<2;++i){ acc3[i][0]=z; acc3[i][1]=z; acc3[i][2]=z; acc3[i][3]=z; }
  gemm64(hidS, HST, C1p, 4, bkS, acc3, t);
  epilogue_store(acc3, bc1, scaleS, hidS, t);     // hidden2 (in-place)
  __syncthreads();

  // cw = hidden2 . Wc2 + cb2
  {
    int eg = t >> 2, g = t & 3;
    float p = 0.f;
    #pragma unroll
    for (int bq=0;bq<4;++bq){
      short8v s = *reinterpret_cast<const short8v*>(&hidS[eg*HST + g*32 + bq*8]);
      #pragma unroll
      for (int j=0;j<8;++j) p += bf2f(s[j]) * wc2S[g*32 + bq*8 + j];
    }
    p += __shfl_xor(p, 1); p += __shfl_xor(p, 2);
    if (g == 0) cwS[eg] = p + cb2[0];
  }
  __syncthreads();

  // x_out[col] += coord_diff * cw (segmented)
  if (t < 6){
    int d = t % 3, half = t / 3;
    int ib = half*32;
    float accx = 0.f;
    int curc = colS[ib];
    for (int j=0;j<32;++j){
      int i = ib + j;
      int cc = colS[i];
      if (cc != curc){
        atomicAdd(&xout[curc*3+d], accx);
        accx = 0.f; curc = cc;
      }
      accx += cdS[i][d] * cwS[i];
    }
    atomicAdd(&xout[curc*3+d], accx);
  }
}

// ---- fused node MLP + next-layer projections ----
// h_new = h + silu(h@Wn1a + magg@Wn1b + bn1)@Wn2 + bn2
// if doProj: A = bf16(h_new@Wcp + b1n), B = bf16(h_new@Wrp)
__global__ __launch_bounds__(256) void node2f_kernel(
    float* __restrict__ h, const float* __restrict__ magg,
    const short* __restrict__ W1ap, const short* __restrict__ W1bp,
    const float* __restrict__ bn1,
    const short* __restrict__ Wn2p, const float* __restrict__ bn2,
    const short* __restrict__ Wcp, const float* __restrict__ b1n,
    const short* __restrict__ Wrp,
    short* __restrict__ A, short* __restrict__ B, int doProj)
{
  __shared__ __align__(16) short hT[ME*HST];
  __shared__ __align__(16) short mT[ME*HST];
  __shared__ __align__(16) short bkS[2*4096];
  const int t = threadIdx.x;
  const int n0 = blockIdx.x * ME;
  {
    int nl = t >> 2, seg = t & 3;
    int n = n0 + nl; if (n >= NN) n = NN-1;
    const float4* hp = reinterpret_cast<const float4*>(h + (size_t)n*HID + seg*32);
    const float4* mp = reinterpret_cast<const float4*>(magg + (size_t)n*HID + seg*32);
    #pragma unroll
    for (int bq=0;bq<4;++bq){
      float4 u = hp[bq*2], v = hp[bq*2+1];
      int4 sv;
      sv.x = (int)cvtpk(u.x,u.y); sv.y = (int)cvtpk(u.z,u.w);
      sv.z = (int)cvtpk(v.x,v.y); sv.w = (int)cvtpk(v.z,v.w);
      *reinterpret_cast<int4*>(&hT[nl*HST + seg*32 + bq*8]) = sv;
      float4 u2 = mp[bq*2], v2 = mp[bq*2+1];
      int4 sv2;
      sv2.x = (int)cvtpk(u2.x,u2.y); sv2.y = (int)cvtpk(u2.z,u2.w);
      sv2.z = (int)cvtpk(v2.x,v2.y); sv2.w = (int)cvtpk(v2.z,v2.w);
      *reinterpret_cast<int4*>(&mT[nl*HST + seg*32 + bq*8]) = sv2;
    }
  }
  f32x4 z = {0.f,0.f,0.f,0.f};
  f32x4 acc[2][4];
  #pragma unroll
  for (int i=0;i<2;++i){ acc[i][0]=z; acc[i][1]=z; acc[i][2]=z; acc[i][3]=z; }
  gemm64(hT, HST, W1ap, 4, bkS, acc, t);
  gemm64(mT, HST, W1bp, 4, bkS, acc, t);        // accumulates
  epilogue_store(acc, bn1, nullptr, mT, t);      // silu1 -> mT (hT preserved? not needed)
  __syncthreads();

  f32x4 acc2[2][4];
  #pragma unroll
  for (int i=0;i<2;++i){ acc2[i][0]=z; acc2[i][1]=z; acc2[i][2]=z; acc2[i][3]=z; }
  gemm64(mT, HST, Wn2p, 4, bkS, acc2, t);

  const int lane = t & 63, w = t >> 6;
  const int q = lane >> 4, fr = lane & 15;
  // h_new -> global h, and bf16(h_new) -> hT for the projection GEMMs
  #pragma unroll
  for (int et=0; et<2; ++et){
    int e0 = (w&1)*32 + et*16 + q*4;
    #pragma unroll
    for (int ot=0; ot<4; ++ot){
      int o = (w>>1)*64 + ot*16 + fr;
      float bv = bn2[o];
      float hn[4];
      #pragma unroll
      for (int r=0;r<4;++r){
        int n = n0 + e0 + r;
        float hv = 0.f;
        if (n < NN){
          size_t idx = (size_t)n*HID + o;
          hv = h[idx] + acc2[et][ot][r] + bv;
          h[idx] = hv;
        }
        hn[r] = hv;
      }
      unsigned p01 = cvtpk(hn[0],hn[1]), p23 = cvtpk(hn[2],hn[3]);
      hT[(e0+0)*HST + o] = (short)p01;
      hT[(e0+1)*HST + o] = (short)(p01>>16);
      hT[(e0+2)*HST + o] = (short)p23;
      hT[(e0+3)*HST + o] = (short)(p23>>16);
    }
  }
  if (!doProj) return;
  // (gemm64's loop-top barrier publishes hT)

  f32x4 accA[2][4], accB[2][4];
  #pragma unroll
  for (int i=0;i<2;++i){ accA[i][0]=z;accA[i][1]=z;accA[i][2]=z;accA[i][3]=z;
                         accB[i][0]=z;accB[i][1]=z;accB[i][2]=z;accB[i][3]=z; }
  gemm64(hT, HST, Wcp, 4, bkS, accA, t);
  gemm64(hT, HST, Wrp, 4, bkS, accB, t);
  #pragma unroll
  for (int et=0; et<2; ++et){
    int e0 = (w&1)*32 + et*16 + q*4;
    #pragma unroll
    for (int ot=0; ot<4; ++ot){
      int o = (w>>1)*64 + ot*16 + fr;
      float bv = b1n[o];
      #pragma unroll
      for (int r=0;r<4;++r){
        int n = n0 + e0 + r;
        if (n < NN){
          A[(size_t)n*HID + o] = bfr(accA[et][ot][r] + bv);
          B[(size_t)n*HID + o] = bfr(accB[et][ot][r]);
        }
      }
    }
  }
}

__global__ void pool_kernel(const float* __restrict__ h, const int* __restrict__ batch,
                            float* __restrict__ sums, float* __restrict__ counts){
  int o  = threadIdx.x;
  int n0 = blockIdx.x * 16;
  int curg = batch[n0];
  float accv = 0.f, cnt = 0.f;
  for (int j=0;j<16;++j){
    int n = n0 + j;
    int g = batch[n];
    if (g != curg){
      atomicAdd(&sums[(size_t)curg*HID+o], accv);
      if (o==0) atomicAdd(&counts[curg], cnt);
      accv = 0.f; cnt = 0.f; curg = g;
    }
    accv += h[(size_t)n*HID+o];
    cnt  += 1.f;
  }
  atomicAdd(&sums[(size_t)curg*HID+o], accv);
  if (o==0) atomicAdd(&counts[curg], cnt);
}

__global__ void out_kernel(const float* __restrict__ sums, const float* __restrict__ counts,
                           const float* __restrict__ rW, const float* __restrict__ rb,
                           float* __restrict__ out){
  int g = blockIdx.x; int t = threadIdx.x;
  float v = sums[(size_t)g*HID + t]*rW[t] + sums[(size_t)g*HID + 64 + t]*rW[64+t];
  #pragma unroll
  for (int off=32; off>0; off>>=1) v += __shfl_down(v, off);
  if (t==0) out[g] = v / fmaxf(counts[g], 1.0f) + rb[0];
}

extern "C" void kernel_launch(void* const* d_in, const int* in_sizes, int n_in,
                              void* d_out, int out_size, void* d_ws, size_t ws_size,
                              hipStream_t stream)
{
  const float* x_feat = (const float*)d_in[0];
  const float* pos    = (const float*)d_in[1];
  const float* eattr  = (const float*)d_in[2];
  const float* p      = (const float*)d_in[3];
  const float* embW   = (const float*)d_in[4];
  const float* embB   = (const float*)d_in[5];
  const float* eW1    = (const float*)d_in[6];
  const float* eb1    = (const float*)d_in[7];
  const float* eW2    = (const float*)d_in[8];
  const float* eb2    = (const float*)d_in[9];
  const float* gW     = (const float*)d_in[10];
  const float* gb     = (const float*)d_in[11];
  const float* nW1    = (const float*)d_in[12];
  const float* nb1    = (const float*)d_in[13];
  const float* nW2    = (const float*)d_in[14];
  const float* nb2    = (const float*)d_in[15];
  const float* cW1    = (const float*)d_in[16];
  const float* cb1    = (const float*)d_in[17];
  const float* cW2    = (const float*)d_in[18];
  const float* cb2    = (const float*)d_in[19];
  const float* rW     = (const float*)d_in[20];
  const float* rb     = (const float*)d_in[21];
  const int* eidx     = (const int*)d_in[22];
  const int* einv     = (const int*)d_in[23];
  const int* batch    = (const int*)d_in[24];

  float* ws = (float*)d_ws;
  float* h      = ws;  ws += (size_t)NN*HID;
  float* magg   = ws;  ws += (size_t)NN*HID;
  float* xA     = ws;  ws += NN*3;
  float* xB     = ws;  ws += NN*3;
  float* sums   = ws;  ws += (size_t)NG*HID;
  float* counts = ws;  ws += NG;
  int*   hist   = (int*)ws;  ws += NN;
  int*   se     = (int*)ws;  ws += NE;
  int2*  rcS    = (int2*)ws;  ws += (size_t)NE*2;
  float4* eaS   = (float4*)ws; ws += (size_t)NE*4;
  float* emS    = ws;  ws += NE;
  short* Abuf = (short*)ws;  ws += (size_t)NN*HID/2;
  short* Bbuf = (short*)ws;  ws += (size_t)NN*HID/2;
  const size_t PK = (size_t)NL*4*4*HID*8;   // shorts per packed array
  short* W1cp  = (short*)ws;
  short* W1rp  = W1cp  + PK;
  short* W2p   = W1rp  + PK;
  short* C1p   = W2p   + PK;
  short* Wn1ap = C1p   + PK;
  short* Wn1bp = Wn1ap + PK;
  short* Wn2p  = Wn1bp + PK;

  // counting sort of edges by col, then materialize sorted streams
  zero_hist<<<(NN+255)/256, 256, 0, stream>>>(hist);
  hist_kernel<<<(NE+255)/256, 256, 0, stream>>>(eidx, hist);
  scan_kernel<<<1, 1024, 0, stream>>>(hist, hist);
  scatter_kernel<<<(NE+255)/256, 256, 0, stream>>>(eidx, hist, se);
  reorder_kernel<<<(NE+255)/256, 256, 0, stream>>>(eidx, se, eattr, p, einv,
                                                   rcS, eaS, emS);

  // prepack bf16 weights (each [L][4][4][128][8])
  const int PG = (int)((PK + 255)/256);
  prepack_kernel<<<PG, 256, 0, stream>>>(eW1, W1cp, 261, 0);
  prepack_kernel<<<PG, 256, 0, stream>>>(eW1, W1rp, 261, 128);
  prepack_kernel<<<PG, 256, 0, stream>>>(eW2, W2p, 128, 0);
  prepack_kernel<<<PG, 256, 0, stream>>>(cW1, C1p, 128, 0);
  prepack_kernel<<<PG, 256, 0, stream>>>(nW1, Wn1ap, 256, 0);
  prepack_kernel<<<PG, 256, 0, stream>>>(nW1, Wn1bp, 256, 128);
  prepack_kernel<<<PG, 256, 0, stream>>>(nW2, Wn2p, 128, 0);

  hipMemcpyAsync(xA, pos, sizeof(float)*NN*3, hipMemcpyDeviceToDevice, stream);
  embed_kernel<<<NN, HID, 0, stream>>>(x_feat, embW, embB, h);
  // layer-0 projections
  nodeproj_kernel<<<NPB, 256, 0, stream>>>(h, W1cp, eb1, W1rp, Abuf, Bbuf);

  float* xc = xA; float* xn = xB;
  for (int l=0;l<NL;++l){
    const size_t wofs = (size_t)l*4*4096;
    const size_t wofsn = (size_t)(l+1)*4*4096;
    hipMemsetAsync(magg, 0, sizeof(float)*(size_t)NN*HID, stream);
    hipMemcpyAsync(xn, xc, sizeof(float)*NN*3, hipMemcpyDeviceToDevice, stream);
    edge2_kernel<<<NWG, 256, 0, stream>>>(Abuf, Bbuf, xc, rcS, eaS, emS,
        eW1 + (size_t)l*261*HID,
        W2p + wofs, eb2 + l*HID,
        gW  + l*HID, gb + l,
        C1p + wofs, cb1 + l*HID,
        cW2 + l*HID, cb2 + l,
        magg, xn);
    int doProj = (l+1 < NL);
    node2f_kernel<<<NPB, 256, 0, stream>>>(h, magg,
        Wn1ap + wofs, Wn1bp + wofs, nb1 + l*HID,
        Wn2p + wofs, nb2 + l*HID,
        W1cp + (doProj?wofsn:0), eb1 + (doProj?(l+1)*HID:0),
        W1rp + (doProj?wofsn:0),
        Abuf, Bbuf, doProj);
    float* tmp = xc; xc = xn; xn = tmp;
  }
  hipMemsetAsync(sums, 0, sizeof(float)*((size_t)NG*HID + NG), stream);
  pool_kernel<<<NN/16, HID, 0, stream>>>(h, batch, sums, counts);
  out_kernel<<<NG, 64, 0, stream>>>(sums, counts, rW, rb, (float*)d_out);
}